// Round 1
// baseline (9012.339 us; speedup 1.0000x reference)
//
#include <hip/hip_runtime.h>
#include <math.h>

#define NNODES  50000
#define NEDGES  1600000
#define NGRAPHS 128
#define HID     128
#define NG      50
#define NITER   3
#define TPTS    8192
#define WMAX    12.0f

__device__ __forceinline__ float ssp(float x) {
    // jax.nn.softplus(x) - log(2) == logaddexp(x,0) - log2
    float sp = fmaxf(x, 0.0f) + log1pf(expf(-fabsf(x)));
    return sp - 0.69314718055994530942f;
}

// ---------------- edge geometry: w[e], C[e] ----------------
__global__ __launch_bounds__(256) void k_geom(const float* __restrict__ pos,
                                              const float* __restrict__ shift,
                                              const int* __restrict__ ei,
                                              float* __restrict__ wArr,
                                              float* __restrict__ cArr)
{
    int e = blockIdx.x * 256 + threadIdx.x;
    if (e >= NEDGES) return;
    int s = ei[e], d = ei[NEDGES + e];
    float rx = pos[3*s+0] - (pos[3*d+0] + shift[3*e+0]);
    float ry = pos[3*s+1] - (pos[3*d+1] + shift[3*e+1]);
    float rz = pos[3*s+2] - (pos[3*d+2] + shift[3*e+2]);
    float w = sqrtf(rx*rx + ry*ry + rz*rz);
    wArr[e] = w;
    cArr[e] = 0.5f * (cosf(w * 3.14159265358979323846f / 8.0f) + 1.0f);
}

// ---------------- h = emb[z] ----------------
__global__ __launch_bounds__(256) void k_init_h(const float* __restrict__ emb,
                                                const int* __restrict__ z,
                                                float* __restrict__ h)
{
    int idx = blockIdx.x * 256 + threadIdx.x;   // N*128 threads
    int n = idx >> 7, c = idx & 127;
    h[idx] = emb[(z[n] << 7) + c];
}

// ---------------- LUT build: table[it][pt][128] = ssp(gauss(w)@W1+b1)@W2+b2 ----------------
__global__ __launch_bounds__(128) void k_table(const float* __restrict__ W1,
                                               const float* __restrict__ B1,
                                               const float* __restrict__ W2,
                                               const float* __restrict__ B2,
                                               float* __restrict__ table)
{
    int it = blockIdx.x / TPTS;
    int pt = blockIdx.x - it * TPTS;
    const float* W1i = W1 + (size_t)it * NG * HID;
    const float* B1i = B1 + (size_t)it * HID;
    const float* W2i = W2 + (size_t)it * HID * HID;
    const float* B2i = B2 + (size_t)it * HID;

    float w = pt * (WMAX / (float)(TPTS - 1));
    __shared__ float sEA[NG];
    __shared__ float sT1[HID];
    int k = threadIdx.x;
    if (k < NG) {
        float dx = 8.0f / 49.0f;
        float coeff = -0.5f / (dx * dx);
        float diff = w - (float)k * dx;
        sEA[k] = expf(coeff * diff * diff);
    }
    __syncthreads();
    float acc = B1i[k];
    for (int g = 0; g < NG; ++g) acc = fmaf(sEA[g], W1i[g * HID + k], acc);
    sT1[k] = ssp(acc);
    __syncthreads();
    float acc2 = B2i[k];
    for (int j = 0; j < HID; ++j) acc2 = fmaf(sT1[j], W2i[j * HID + k], acc2);
    table[(size_t)blockIdx.x * HID + k] = acc2;
}

// ---------------- node GEMM: out[r] = A[r] @ W (+bias), rows tiled 64/block ----------------
__global__ __launch_bounds__(256) void k_node_gemm(const float* __restrict__ A,
                                                   const float* __restrict__ W,
                                                   const float* __restrict__ bias,
                                                   float* __restrict__ out)
{
    __shared__ float sA[64 * 132];
    int r0 = blockIdx.x * 64;
    int tid = threadIdx.x;
    for (int idx = tid; idx < 64 * 32; idx += 256) {
        int r = idx >> 5, c4 = idx & 31;
        int row = r0 + r;
        float4 v = make_float4(0.f, 0.f, 0.f, 0.f);
        if (row < NNODES) v = *(const float4*)(A + (size_t)row * HID + c4 * 4);
        *(float4*)(&sA[r * 132 + c4 * 4]) = v;
    }
    __syncthreads();
    int tx = tid & 15, ty = tid >> 4;
    int cc = tx * 8, ee = ty * 4;
    float acc[4][8];
    if (bias) {
        float4 b0 = *(const float4*)(bias + cc);
        float4 b1 = *(const float4*)(bias + cc + 4);
        #pragma unroll
        for (int e = 0; e < 4; ++e) {
            acc[e][0]=b0.x; acc[e][1]=b0.y; acc[e][2]=b0.z; acc[e][3]=b0.w;
            acc[e][4]=b1.x; acc[e][5]=b1.y; acc[e][6]=b1.z; acc[e][7]=b1.w;
        }
    } else {
        #pragma unroll
        for (int e = 0; e < 4; ++e)
            #pragma unroll
            for (int c = 0; c < 8; ++c) acc[e][c] = 0.f;
    }
    for (int j = 0; j < HID; ++j) {
        float a[4];
        #pragma unroll
        for (int e = 0; e < 4; ++e) a[e] = sA[(ee + e) * 132 + j];
        float4 w0 = *(const float4*)(W + (size_t)j * HID + cc);
        float4 w1 = *(const float4*)(W + (size_t)j * HID + cc + 4);
        float wv[8] = {w0.x,w0.y,w0.z,w0.w,w1.x,w1.y,w1.z,w1.w};
        #pragma unroll
        for (int e = 0; e < 4; ++e)
            #pragma unroll
            for (int c = 0; c < 8; ++c)
                acc[e][c] = fmaf(a[e], wv[c], acc[e][c]);
    }
    #pragma unroll
    for (int e = 0; e < 4; ++e) {
        int row = r0 + ee + e;
        if (row < NNODES) {
            float4 o0 = make_float4(acc[e][0], acc[e][1], acc[e][2], acc[e][3]);
            float4 o1 = make_float4(acc[e][4], acc[e][5], acc[e][6], acc[e][7]);
            *(float4*)(out + (size_t)row * HID + cc) = o0;
            *(float4*)(out + (size_t)row * HID + cc + 4) = o1;
        }
    }
}

// ---------------- edge message + scatter: agg[dst] += lerp(table,w)*C*hf[src] ----------------
__global__ __launch_bounds__(256) void k_edge(const float* __restrict__ wArr,
                                              const float* __restrict__ cArr,
                                              const int* __restrict__ ei,
                                              const float* __restrict__ hf,
                                              const float* __restrict__ table,
                                              float* __restrict__ agg)
{
    int eidx = blockIdx.x * 8 + (threadIdx.x >> 5);
    int lane = threadIdx.x & 31;
    float w = wArr[eidx];
    float C = cArr[eidx];
    int s = ei[eidx], d = ei[NEDGES + eidx];
    float t = fminf(w * ((float)(TPTS - 1) / WMAX), (float)(TPTS - 1));
    int i0 = (int)t;
    if (i0 > TPTS - 2) i0 = TPTS - 2;
    float fr = t - (float)i0;
    const float4* r0p = (const float4*)(table + (size_t)i0 * HID) + lane;
    const float4* r1p = r0p + HID / 4;
    float4 a = *r0p;
    float4 b = *r1p;
    float4 hv = *((const float4*)(hf + (size_t)s * HID) + lane);
    float m0 = fmaf(fr, b.x - a.x, a.x) * C * hv.x;
    float m1 = fmaf(fr, b.y - a.y, a.y) * C * hv.y;
    float m2 = fmaf(fr, b.z - a.z, a.z) * C * hv.z;
    float m3 = fmaf(fr, b.w - a.w, a.w) * C * hv.w;
    float* ap = agg + (size_t)d * HID + lane * 4;
    atomicAdd(ap + 0, m0);
    atomicAdd(ap + 1, m1);
    atomicAdd(ap + 2, m2);
    atomicAdd(ap + 3, m3);
}

// ---------------- node update: h += ssp(agg@W2+b2)@L+lb ----------------
__global__ __launch_bounds__(256) void k_node_update(const float* __restrict__ agg,
                                                     const float* __restrict__ W,
                                                     const float* __restrict__ B,
                                                     const float* __restrict__ L,
                                                     const float* __restrict__ LB,
                                                     float* __restrict__ h)
{
    __shared__ float sA[64 * 132];
    __shared__ float sT[64 * 132];
    int r0 = blockIdx.x * 64;
    int tid = threadIdx.x;
    for (int idx = tid; idx < 64 * 32; idx += 256) {
        int r = idx >> 5, c4 = idx & 31;
        int row = r0 + r;
        float4 v = make_float4(0.f, 0.f, 0.f, 0.f);
        if (row < NNODES) v = *(const float4*)(agg + (size_t)row * HID + c4 * 4);
        *(float4*)(&sA[r * 132 + c4 * 4]) = v;
    }
    __syncthreads();
    int tx = tid & 15, ty = tid >> 4;
    int cc = tx * 8, ee = ty * 4;
    float acc[4][8];
    {
        float4 b0 = *(const float4*)(B + cc);
        float4 b1 = *(const float4*)(B + cc + 4);
        #pragma unroll
        for (int e = 0; e < 4; ++e) {
            acc[e][0]=b0.x; acc[e][1]=b0.y; acc[e][2]=b0.z; acc[e][3]=b0.w;
            acc[e][4]=b1.x; acc[e][5]=b1.y; acc[e][6]=b1.z; acc[e][7]=b1.w;
        }
    }
    for (int j = 0; j < HID; ++j) {
        float a[4];
        #pragma unroll
        for (int e = 0; e < 4; ++e) a[e] = sA[(ee + e) * 132 + j];
        float4 w0 = *(const float4*)(W + (size_t)j * HID + cc);
        float4 w1 = *(const float4*)(W + (size_t)j * HID + cc + 4);
        float wv[8] = {w0.x,w0.y,w0.z,w0.w,w1.x,w1.y,w1.z,w1.w};
        #pragma unroll
        for (int e = 0; e < 4; ++e)
            #pragma unroll
            for (int c = 0; c < 8; ++c)
                acc[e][c] = fmaf(a[e], wv[c], acc[e][c]);
    }
    #pragma unroll
    for (int e = 0; e < 4; ++e)
        #pragma unroll
        for (int c = 0; c < 8; ++c)
            sT[(ee + e) * 132 + cc + c] = ssp(acc[e][c]);
    __syncthreads();
    float acc2[4][8];
    {
        float4 b0 = *(const float4*)(LB + cc);
        float4 b1 = *(const float4*)(LB + cc + 4);
        #pragma unroll
        for (int e = 0; e < 4; ++e) {
            acc2[e][0]=b0.x; acc2[e][1]=b0.y; acc2[e][2]=b0.z; acc2[e][3]=b0.w;
            acc2[e][4]=b1.x; acc2[e][5]=b1.y; acc2[e][6]=b1.z; acc2[e][7]=b1.w;
        }
    }
    for (int j = 0; j < HID; ++j) {
        float a[4];
        #pragma unroll
        for (int e = 0; e < 4; ++e) a[e] = sT[(ee + e) * 132 + j];
        float4 w0 = *(const float4*)(L + (size_t)j * HID + cc);
        float4 w1 = *(const float4*)(L + (size_t)j * HID + cc + 4);
        float wv[8] = {w0.x,w0.y,w0.z,w0.w,w1.x,w1.y,w1.z,w1.w};
        #pragma unroll
        for (int e = 0; e < 4; ++e)
            #pragma unroll
            for (int c = 0; c < 8; ++c)
                acc2[e][c] = fmaf(a[e], wv[c], acc2[e][c]);
    }
    #pragma unroll
    for (int e = 0; e < 4; ++e) {
        int row = r0 + ee + e;
        if (row < NNODES) {
            float4* hp0 = (float4*)(h + (size_t)row * HID + cc);
            float4* hp1 = (float4*)(h + (size_t)row * HID + cc + 4);
            float4 h0 = *hp0, h1 = *hp1;
            h0.x += acc2[e][0]; h0.y += acc2[e][1]; h0.z += acc2[e][2]; h0.w += acc2[e][3];
            h1.x += acc2[e][4]; h1.y += acc2[e][5]; h1.z += acc2[e][6]; h1.w += acc2[e][7];
            *hp0 = h0; *hp1 = h1;
        }
    }
}

// ---------------- head: out_atom per node -> atomic into per-graph sums/counts ----------------
__global__ __launch_bounds__(256) void k_head(const float* __restrict__ h,
                                              const float* __restrict__ w1,
                                              const float* __restrict__ b1,
                                              const float* __restrict__ w2,
                                              const float* __restrict__ b2,
                                              const int* __restrict__ batch,
                                              float* __restrict__ sums,
                                              float* __restrict__ counts)
{
    __shared__ float sH[4][128];
    int wv = threadIdx.x >> 6, lane = threadIdx.x & 63;
    int node = blockIdx.x * 4 + wv;   // NNODES divisible by 4
    sH[wv][lane]      = h[(size_t)node * HID + lane];
    sH[wv][lane + 64] = h[(size_t)node * HID + 64 + lane];
    __syncthreads();
    float acc = b1[lane];
    for (int j = 0; j < HID; ++j) acc = fmaf(sH[wv][j], w1[j * 64 + lane], acc);
    float t = ssp(acc);
    float contrib = t * w2[lane];
    for (int off = 32; off > 0; off >>= 1) contrib += __shfl_down(contrib, off);
    if (lane == 0) {
        int b = batch[node];
        atomicAdd(&sums[b], contrib + b2[0]);
        atomicAdd(&counts[b], 1.0f);
    }
}

__global__ void k_final(const float* __restrict__ sums,
                        const float* __restrict__ counts,
                        float* __restrict__ out)
{
    int g = threadIdx.x;
    if (g < NGRAPHS) out[g] = sums[g] / fmaxf(counts[g], 1.0f);
}

extern "C" void kernel_launch(void* const* d_in, const int* in_sizes, int n_in,
                              void* d_out, int out_size, void* d_ws, size_t ws_size,
                              hipStream_t stream)
{
    const float* pos     = (const float*)d_in[0];
    const float* shift   = (const float*)d_in[1];
    const float* emb     = (const float*)d_in[2];
    const float* mlp_w1  = (const float*)d_in[3];
    const float* mlp_b1  = (const float*)d_in[4];
    const float* mlp_w2  = (const float*)d_in[5];
    const float* mlp_b2  = (const float*)d_in[6];
    const float* cf_w1   = (const float*)d_in[7];
    const float* cf_w2   = (const float*)d_in[8];
    const float* cf_b2   = (const float*)d_in[9];
    const float* lin_w   = (const float*)d_in[10];
    const float* lin_b   = (const float*)d_in[11];
    const float* head_w1 = (const float*)d_in[12];
    const float* head_b1 = (const float*)d_in[13];
    const float* head_w2 = (const float*)d_in[14];
    const float* head_b2 = (const float*)d_in[15];
    const int*   z       = (const int*)d_in[16];
    const int*   ei      = (const int*)d_in[17];
    const int*   batch   = (const int*)d_in[18];
    float* out = (float*)d_out;

    float* ws = (float*)d_ws;
    size_t off = 0;
    float* wArr   = ws + off; off += NEDGES;
    float* cArr   = ws + off; off += NEDGES;
    float* h      = ws + off; off += (size_t)NNODES * HID;
    float* hf     = ws + off; off += (size_t)NNODES * HID;
    float* agg    = ws + off; off += (size_t)NNODES * HID;
    float* table  = ws + off; off += (size_t)3 * TPTS * HID;
    float* sums   = ws + off; off += NGRAPHS;
    float* counts = ws + off; off += NGRAPHS;

    hipMemsetAsync(sums, 0, 2 * NGRAPHS * sizeof(float), stream);  // sums+counts contiguous
    k_geom<<<NEDGES / 256, 256, 0, stream>>>(pos, shift, ei, wArr, cArr);
    k_init_h<<<NNODES * HID / 256, 256, 0, stream>>>(emb, z, h);
    k_table<<<3 * TPTS, 128, 0, stream>>>(mlp_w1, mlp_b1, mlp_w2, mlp_b2, table);

    for (int i = 0; i < NITER; ++i) {
        k_node_gemm<<<(NNODES + 63) / 64, 256, 0, stream>>>(h, cf_w1 + (size_t)i * HID * HID, nullptr, hf);
        hipMemsetAsync(agg, 0, (size_t)NNODES * HID * sizeof(float), stream);
        k_edge<<<NEDGES / 8, 256, 0, stream>>>(wArr, cArr, ei, hf, table + (size_t)i * TPTS * HID, agg);
        k_node_update<<<(NNODES + 63) / 64, 256, 0, stream>>>(agg, cf_w2 + (size_t)i * HID * HID,
                                                              cf_b2 + (size_t)i * HID,
                                                              lin_w + (size_t)i * HID * HID,
                                                              lin_b + (size_t)i * HID, h);
    }
    k_head<<<NNODES / 4, 256, 0, stream>>>(h, head_w1, head_b1, head_w2, head_b2, batch, sums, counts);
    k_final<<<1, 128, 0, stream>>>(sums, counts, out);
}

// Round 2
// 1795.842 us; speedup vs baseline: 5.0184x; 5.0184x over previous
//
#include <hip/hip_runtime.h>
#include <math.h>

#define NNODES  50000
#define NEDGES  1600000
#define NGRAPHS 128
#define HID     128
#define NG      50
#define NITER   3
#define TPTS    8192
#define WMAX    12.0f
#define PI_F    3.14159265358979323846f

__device__ __forceinline__ float ssp(float x) {
    float sp = fmaxf(x, 0.0f) + log1pf(expf(-fabsf(x)));
    return sp - 0.69314718055994530942f;
}

// ---------------- h = emb[z] ----------------
__global__ __launch_bounds__(256) void k_init_h(const float* __restrict__ emb,
                                                const int* __restrict__ z,
                                                float* __restrict__ h)
{
    int idx = blockIdx.x * 256 + threadIdx.x;
    int n = idx >> 7, c = idx & 127;
    h[idx] = emb[(z[n] << 7) + c];
}

// ---------------- LUT build ----------------
__global__ __launch_bounds__(128) void k_table(const float* __restrict__ W1,
                                               const float* __restrict__ B1,
                                               const float* __restrict__ W2,
                                               const float* __restrict__ B2,
                                               float* __restrict__ table)
{
    int it = blockIdx.x / TPTS;
    int pt = blockIdx.x - it * TPTS;
    const float* W1i = W1 + (size_t)it * NG * HID;
    const float* B1i = B1 + (size_t)it * HID;
    const float* W2i = W2 + (size_t)it * HID * HID;
    const float* B2i = B2 + (size_t)it * HID;

    float w = pt * (WMAX / (float)(TPTS - 1));
    __shared__ float sEA[NG];
    __shared__ float sT1[HID];
    int k = threadIdx.x;
    if (k < NG) {
        float dx = 8.0f / 49.0f;
        float coeff = -0.5f / (dx * dx);
        float diff = w - (float)k * dx;
        sEA[k] = expf(coeff * diff * diff);
    }
    __syncthreads();
    float acc = B1i[k];
    for (int g = 0; g < NG; ++g) acc = fmaf(sEA[g], W1i[g * HID + k], acc);
    sT1[k] = ssp(acc);
    __syncthreads();
    float acc2 = B2i[k];
    for (int j = 0; j < HID; ++j) acc2 = fmaf(sT1[j], W2i[j * HID + k], acc2);
    table[(size_t)blockIdx.x * HID + k] = acc2;
}

// ---------------- CSR build: histogram of dst ----------------
__global__ __launch_bounds__(256) void k_hist(const int* __restrict__ ei,
                                              int* __restrict__ deg)
{
    int e = blockIdx.x * 256 + threadIdx.x;
    if (e >= NEDGES) return;
    atomicAdd(&deg[ei[NEDGES + e]], 1);
}

// ---------------- CSR build: exclusive scan (single block) ----------------
#define SCAN_T 1024
__global__ __launch_bounds__(SCAN_T) void k_scan(const int* __restrict__ deg,
                                                 int* __restrict__ rowptr,
                                                 int* __restrict__ cursor)
{
    __shared__ int s[SCAN_T];
    __shared__ int sOff;
    int tid = threadIdx.x;
    if (tid == 0) sOff = 0;
    __syncthreads();
    for (int base = 0; base < NNODES; base += SCAN_T) {
        int i = base + tid;
        int v = (i < NNODES) ? deg[i] : 0;
        s[tid] = v;
        __syncthreads();
        for (int d = 1; d < SCAN_T; d <<= 1) {
            int t = (tid >= d) ? s[tid - d] : 0;
            __syncthreads();
            s[tid] += t;
            __syncthreads();
        }
        int inc = s[tid];
        int off = sOff;
        if (i < NNODES) { rowptr[i] = off + inc - v; cursor[i] = off + inc - v; }
        __syncthreads();
        if (tid == SCAN_T - 1) sOff = off + inc;
        __syncthreads();
    }
    if (tid == 0) rowptr[NNODES] = sOff;
}

// ---------------- CSR build: scatter edge records (src, w) sorted by dst ----------------
__global__ __launch_bounds__(256) void k_scatter(const int* __restrict__ ei,
                                                 const float* __restrict__ pos,
                                                 const float* __restrict__ shift,
                                                 int* __restrict__ cursor,
                                                 float2* __restrict__ rec)
{
    int e = blockIdx.x * 256 + threadIdx.x;
    if (e >= NEDGES) return;
    int s = ei[e], d = ei[NEDGES + e];
    float rx = pos[3*s+0] - (pos[3*d+0] + shift[3*e+0]);
    float ry = pos[3*s+1] - (pos[3*d+1] + shift[3*e+1]);
    float rz = pos[3*s+2] - (pos[3*d+2] + shift[3*e+2]);
    float w = sqrtf(rx*rx + ry*ry + rz*rz);
    int slot = atomicAdd(&cursor[d], 1);
    rec[slot] = make_float2(__int_as_float(s), w);
}

// ---------------- gather-aggregate: one wave per dst node ----------------
__global__ __launch_bounds__(256) void k_gather(const float2* __restrict__ rec,
                                                const int* __restrict__ rowptr,
                                                const float* __restrict__ hf,
                                                const float* __restrict__ table,
                                                float* __restrict__ agg)
{
    int node = blockIdx.x * 4 + (threadIdx.x >> 6);
    int lane = threadIdx.x & 63;
    int beg = rowptr[node], end = rowptr[node + 1];
    float2 acc = make_float2(0.f, 0.f);
    for (int k = beg; k < end; ++k) {
        float2 r = rec[k];
        int   src = __float_as_int(r.x);
        float w   = r.y;
        float C = 0.5f * (cosf(w * (PI_F / 8.0f)) + 1.0f);
        float t = fminf(w * ((float)(TPTS - 1) / WMAX), (float)(TPTS - 1));
        int i0 = (int)t;
        if (i0 > TPTS - 2) i0 = TPTS - 2;
        float fr = t - (float)i0;
        float2 ta = *(const float2*)(table + (size_t)i0 * HID + lane * 2);
        float2 tb = *(const float2*)(table + (size_t)(i0 + 1) * HID + lane * 2);
        float2 hv = *(const float2*)(hf + (size_t)src * HID + lane * 2);
        float f0 = fmaf(fr, tb.x - ta.x, ta.x) * C;
        float f1 = fmaf(fr, tb.y - ta.y, ta.y) * C;
        acc.x = fmaf(f0, hv.x, acc.x);
        acc.y = fmaf(f1, hv.y, acc.y);
    }
    *(float2*)(agg + (size_t)node * HID + lane * 2) = acc;
}

// ---------------- node GEMM: out[r] = A[r] @ W (+bias) ----------------
__global__ __launch_bounds__(256) void k_node_gemm(const float* __restrict__ A,
                                                   const float* __restrict__ W,
                                                   const float* __restrict__ bias,
                                                   float* __restrict__ out)
{
    __shared__ float sA[64 * 132];
    int r0 = blockIdx.x * 64;
    int tid = threadIdx.x;
    for (int idx = tid; idx < 64 * 32; idx += 256) {
        int r = idx >> 5, c4 = idx & 31;
        int row = r0 + r;
        float4 v = make_float4(0.f, 0.f, 0.f, 0.f);
        if (row < NNODES) v = *(const float4*)(A + (size_t)row * HID + c4 * 4);
        *(float4*)(&sA[r * 132 + c4 * 4]) = v;
    }
    __syncthreads();
    int tx = tid & 15, ty = tid >> 4;
    int cc = tx * 8, ee = ty * 4;
    float acc[4][8];
    if (bias) {
        float4 b0 = *(const float4*)(bias + cc);
        float4 b1 = *(const float4*)(bias + cc + 4);
        #pragma unroll
        for (int e = 0; e < 4; ++e) {
            acc[e][0]=b0.x; acc[e][1]=b0.y; acc[e][2]=b0.z; acc[e][3]=b0.w;
            acc[e][4]=b1.x; acc[e][5]=b1.y; acc[e][6]=b1.z; acc[e][7]=b1.w;
        }
    } else {
        #pragma unroll
        for (int e = 0; e < 4; ++e)
            #pragma unroll
            for (int c = 0; c < 8; ++c) acc[e][c] = 0.f;
    }
    for (int j = 0; j < HID; ++j) {
        float a[4];
        #pragma unroll
        for (int e = 0; e < 4; ++e) a[e] = sA[(ee + e) * 132 + j];
        float4 w0 = *(const float4*)(W + (size_t)j * HID + cc);
        float4 w1 = *(const float4*)(W + (size_t)j * HID + cc + 4);
        float wv[8] = {w0.x,w0.y,w0.z,w0.w,w1.x,w1.y,w1.z,w1.w};
        #pragma unroll
        for (int e = 0; e < 4; ++e)
            #pragma unroll
            for (int c = 0; c < 8; ++c)
                acc[e][c] = fmaf(a[e], wv[c], acc[e][c]);
    }
    #pragma unroll
    for (int e = 0; e < 4; ++e) {
        int row = r0 + ee + e;
        if (row < NNODES) {
            *(float4*)(out + (size_t)row * HID + cc)     = make_float4(acc[e][0], acc[e][1], acc[e][2], acc[e][3]);
            *(float4*)(out + (size_t)row * HID + cc + 4) = make_float4(acc[e][4], acc[e][5], acc[e][6], acc[e][7]);
        }
    }
}

// ---------------- node update: h += ssp(agg@W2+b2)@L+lb ----------------
__global__ __launch_bounds__(256) void k_node_update(const float* __restrict__ agg,
                                                     const float* __restrict__ W,
                                                     const float* __restrict__ B,
                                                     const float* __restrict__ L,
                                                     const float* __restrict__ LB,
                                                     float* __restrict__ h)
{
    __shared__ float sA[64 * 132];
    __shared__ float sT[64 * 132];
    int r0 = blockIdx.x * 64;
    int tid = threadIdx.x;
    for (int idx = tid; idx < 64 * 32; idx += 256) {
        int r = idx >> 5, c4 = idx & 31;
        int row = r0 + r;
        float4 v = make_float4(0.f, 0.f, 0.f, 0.f);
        if (row < NNODES) v = *(const float4*)(agg + (size_t)row * HID + c4 * 4);
        *(float4*)(&sA[r * 132 + c4 * 4]) = v;
    }
    __syncthreads();
    int tx = tid & 15, ty = tid >> 4;
    int cc = tx * 8, ee = ty * 4;
    float acc[4][8];
    {
        float4 b0 = *(const float4*)(B + cc);
        float4 b1 = *(const float4*)(B + cc + 4);
        #pragma unroll
        for (int e = 0; e < 4; ++e) {
            acc[e][0]=b0.x; acc[e][1]=b0.y; acc[e][2]=b0.z; acc[e][3]=b0.w;
            acc[e][4]=b1.x; acc[e][5]=b1.y; acc[e][6]=b1.z; acc[e][7]=b1.w;
        }
    }
    for (int j = 0; j < HID; ++j) {
        float a[4];
        #pragma unroll
        for (int e = 0; e < 4; ++e) a[e] = sA[(ee + e) * 132 + j];
        float4 w0 = *(const float4*)(W + (size_t)j * HID + cc);
        float4 w1 = *(const float4*)(W + (size_t)j * HID + cc + 4);
        float wv[8] = {w0.x,w0.y,w0.z,w0.w,w1.x,w1.y,w1.z,w1.w};
        #pragma unroll
        for (int e = 0; e < 4; ++e)
            #pragma unroll
            for (int c = 0; c < 8; ++c)
                acc[e][c] = fmaf(a[e], wv[c], acc[e][c]);
    }
    #pragma unroll
    for (int e = 0; e < 4; ++e)
        #pragma unroll
        for (int c = 0; c < 8; ++c)
            sT[(ee + e) * 132 + cc + c] = ssp(acc[e][c]);
    __syncthreads();
    float acc2[4][8];
    {
        float4 b0 = *(const float4*)(LB + cc);
        float4 b1 = *(const float4*)(LB + cc + 4);
        #pragma unroll
        for (int e = 0; e < 4; ++e) {
            acc2[e][0]=b0.x; acc2[e][1]=b0.y; acc2[e][2]=b0.z; acc2[e][3]=b0.w;
            acc2[e][4]=b1.x; acc2[e][5]=b1.y; acc2[e][6]=b1.z; acc2[e][7]=b1.w;
        }
    }
    for (int j = 0; j < HID; ++j) {
        float a[4];
        #pragma unroll
        for (int e = 0; e < 4; ++e) a[e] = sT[(ee + e) * 132 + j];
        float4 w0 = *(const float4*)(L + (size_t)j * HID + cc);
        float4 w1 = *(const float4*)(L + (size_t)j * HID + cc + 4);
        float wv[8] = {w0.x,w0.y,w0.z,w0.w,w1.x,w1.y,w1.z,w1.w};
        #pragma unroll
        for (int e = 0; e < 4; ++e)
            #pragma unroll
            for (int c = 0; c < 8; ++c)
                acc2[e][c] = fmaf(a[e], wv[c], acc2[e][c]);
    }
    #pragma unroll
    for (int e = 0; e < 4; ++e) {
        int row = r0 + ee + e;
        if (row < NNODES) {
            float4* hp0 = (float4*)(h + (size_t)row * HID + cc);
            float4* hp1 = (float4*)(h + (size_t)row * HID + cc + 4);
            float4 h0 = *hp0, h1 = *hp1;
            h0.x += acc2[e][0]; h0.y += acc2[e][1]; h0.z += acc2[e][2]; h0.w += acc2[e][3];
            h1.x += acc2[e][4]; h1.y += acc2[e][5]; h1.z += acc2[e][6]; h1.w += acc2[e][7];
            *hp0 = h0; *hp1 = h1;
        }
    }
}

// ---------------- head ----------------
__global__ __launch_bounds__(256) void k_head(const float* __restrict__ h,
                                              const float* __restrict__ w1,
                                              const float* __restrict__ b1,
                                              const float* __restrict__ w2,
                                              const float* __restrict__ b2,
                                              const int* __restrict__ batch,
                                              float* __restrict__ sums,
                                              float* __restrict__ counts)
{
    __shared__ float sH[4][128];
    int wv = threadIdx.x >> 6, lane = threadIdx.x & 63;
    int node = blockIdx.x * 4 + wv;
    sH[wv][lane]      = h[(size_t)node * HID + lane];
    sH[wv][lane + 64] = h[(size_t)node * HID + 64 + lane];
    __syncthreads();
    float acc = b1[lane];
    for (int j = 0; j < HID; ++j) acc = fmaf(sH[wv][j], w1[j * 64 + lane], acc);
    float t = ssp(acc);
    float contrib = t * w2[lane];
    for (int off = 32; off > 0; off >>= 1) contrib += __shfl_down(contrib, off);
    if (lane == 0) {
        int b = batch[node];
        atomicAdd(&sums[b], contrib + b2[0]);
        atomicAdd(&counts[b], 1.0f);
    }
}

__global__ void k_final(const float* __restrict__ sums,
                        const float* __restrict__ counts,
                        float* __restrict__ out)
{
    int g = threadIdx.x;
    if (g < NGRAPHS) out[g] = sums[g] / fmaxf(counts[g], 1.0f);
}

extern "C" void kernel_launch(void* const* d_in, const int* in_sizes, int n_in,
                              void* d_out, int out_size, void* d_ws, size_t ws_size,
                              hipStream_t stream)
{
    const float* pos     = (const float*)d_in[0];
    const float* shift   = (const float*)d_in[1];
    const float* emb     = (const float*)d_in[2];
    const float* mlp_w1  = (const float*)d_in[3];
    const float* mlp_b1  = (const float*)d_in[4];
    const float* mlp_w2  = (const float*)d_in[5];
    const float* mlp_b2  = (const float*)d_in[6];
    const float* cf_w1   = (const float*)d_in[7];
    const float* cf_w2   = (const float*)d_in[8];
    const float* cf_b2   = (const float*)d_in[9];
    const float* lin_w   = (const float*)d_in[10];
    const float* lin_b   = (const float*)d_in[11];
    const float* head_w1 = (const float*)d_in[12];
    const float* head_b1 = (const float*)d_in[13];
    const float* head_w2 = (const float*)d_in[14];
    const float* head_b2 = (const float*)d_in[15];
    const int*   z       = (const int*)d_in[16];
    const int*   ei      = (const int*)d_in[17];
    const int*   batch   = (const int*)d_in[18];
    float* out = (float*)d_out;

    float* ws = (float*)d_ws;
    size_t off = 0;
    float*  h      = ws + off; off += (size_t)NNODES * HID;
    float*  hf     = ws + off; off += (size_t)NNODES * HID;
    float*  agg    = ws + off; off += (size_t)NNODES * HID;
    float*  table  = ws + off; off += (size_t)3 * TPTS * HID;
    float2* rec    = (float2*)(ws + off); off += (size_t)2 * NEDGES;
    int*    rowptr = (int*)(ws + off); off += NNODES + 1;
    int*    deg    = (int*)(ws + off); off += NNODES;
    int*    cursor = (int*)(ws + off); off += NNODES;
    float*  sums   = ws + off; off += NGRAPHS;
    float*  counts = ws + off; off += NGRAPHS;

    hipMemsetAsync(deg, 0, NNODES * sizeof(int), stream);
    hipMemsetAsync(sums, 0, 2 * NGRAPHS * sizeof(float), stream);

    k_hist<<<(NEDGES + 255) / 256, 256, 0, stream>>>(ei, deg);
    k_scan<<<1, SCAN_T, 0, stream>>>(deg, rowptr, cursor);
    k_scatter<<<(NEDGES + 255) / 256, 256, 0, stream>>>(ei, pos, shift, cursor, rec);

    k_init_h<<<NNODES * HID / 256, 256, 0, stream>>>(emb, z, h);
    k_table<<<3 * TPTS, 128, 0, stream>>>(mlp_w1, mlp_b1, mlp_w2, mlp_b2, table);

    for (int i = 0; i < NITER; ++i) {
        k_node_gemm<<<(NNODES + 63) / 64, 256, 0, stream>>>(h, cf_w1 + (size_t)i * HID * HID, nullptr, hf);
        k_gather<<<(NNODES + 3) / 4, 256, 0, stream>>>(rec, rowptr, hf, table + (size_t)i * TPTS * HID, agg);
        k_node_update<<<(NNODES + 63) / 64, 256, 0, stream>>>(agg, cf_w2 + (size_t)i * HID * HID,
                                                              cf_b2 + (size_t)i * HID,
                                                              lin_w + (size_t)i * HID * HID,
                                                              lin_b + (size_t)i * HID, h);
    }
    k_head<<<NNODES / 4, 256, 0, stream>>>(h, head_w1, head_b1, head_w2, head_b2, batch, sums, counts);
    k_final<<<1, 128, 0, stream>>>(sums, counts, out);
}

// Round 3
// 1226.709 us; speedup vs baseline: 7.3468x; 1.4640x over previous
//
#include <hip/hip_runtime.h>
#include <math.h>

#define NNODES  50000
#define NEDGES  1600000
#define NGRAPHS 128
#define HID     128
#define NG      50
#define NITER   3
#define TPTS    2048
#define WMAX    12.0f
#define PI_F    3.14159265358979323846f

__device__ __forceinline__ float ssp(float x) {
    float sp = fmaxf(x, 0.0f) + log1pf(expf(-fabsf(x)));
    return sp - 0.69314718055994530942f;
}

// ---------------- h = emb[z] ----------------
__global__ __launch_bounds__(256) void k_init_h(const float* __restrict__ emb,
                                                const int* __restrict__ z,
                                                float* __restrict__ h)
{
    int idx = blockIdx.x * 256 + threadIdx.x;
    int n = idx >> 7, c = idx & 127;
    h[idx] = emb[(z[n] << 7) + c];
}

// ---------------- LUT build (raw, no cutoff folded) ----------------
__global__ __launch_bounds__(128) void k_table(const float* __restrict__ W1,
                                               const float* __restrict__ B1,
                                               const float* __restrict__ W2,
                                               const float* __restrict__ B2,
                                               float* __restrict__ table)
{
    int it = blockIdx.x / TPTS;
    int pt = blockIdx.x - it * TPTS;
    const float* W1i = W1 + (size_t)it * NG * HID;
    const float* B1i = B1 + (size_t)it * HID;
    const float* W2i = W2 + (size_t)it * HID * HID;
    const float* B2i = B2 + (size_t)it * HID;

    float w = pt * (WMAX / (float)(TPTS - 1));
    __shared__ float sEA[NG];
    __shared__ float sT1[HID];
    int k = threadIdx.x;
    if (k < NG) {
        float dx = 8.0f / 49.0f;
        float coeff = -0.5f / (dx * dx);
        float diff = w - (float)k * dx;
        sEA[k] = expf(coeff * diff * diff);
    }
    __syncthreads();
    float acc = B1i[k];
    for (int g = 0; g < NG; ++g) acc = fmaf(sEA[g], W1i[g * HID + k], acc);
    sT1[k] = ssp(acc);
    __syncthreads();
    float acc2 = B2i[k];
    for (int j = 0; j < HID; ++j) acc2 = fmaf(sT1[j], W2i[j * HID + k], acc2);
    table[(size_t)blockIdx.x * HID + k] = acc2;
}

// ---------------- interleave (val, delta) ----------------
__global__ __launch_bounds__(256) void k_tdelta(const float* __restrict__ raw,
                                                float* __restrict__ ti)
{
    int idx = blockIdx.x * 256 + threadIdx.x;   // 3*TPTS*128
    int c = idx & 127;
    int pt_it = idx >> 7;
    int pt = pt_it & (TPTS - 1);
    float v = raw[idx];
    float nv = (pt == TPTS - 1) ? v : raw[idx + HID];
    ti[(size_t)pt_it * 256 + c * 2]     = v;
    ti[(size_t)pt_it * 256 + c * 2 + 1] = nv - v;
}

// ---------------- CSR build: histogram of dst ----------------
__global__ __launch_bounds__(256) void k_hist(const int* __restrict__ ei,
                                              int* __restrict__ deg)
{
    int e = blockIdx.x * 256 + threadIdx.x;
    if (e >= NEDGES) return;
    atomicAdd(&deg[ei[NEDGES + e]], 1);
}

// ---------------- CSR build: exclusive scan, chunk-per-thread ----------------
#define SCAN_T 1024
#define CHUNK  49
__global__ __launch_bounds__(SCAN_T) void k_scan(const int* __restrict__ deg,
                                                 int* __restrict__ rowptr,
                                                 int* __restrict__ cursor)
{
    int tid = threadIdx.x;
    int base = tid * CHUNK;
    int vals[CHUNK];
    int local = 0;
    #pragma unroll
    for (int i = 0; i < CHUNK; ++i) {
        int idx = base + i;
        int v = (idx < NNODES) ? deg[idx] : 0;
        vals[i] = local;
        local += v;
    }
    int lane = tid & 63, wid = tid >> 6;
    int x = local;
    #pragma unroll
    for (int off = 1; off < 64; off <<= 1) {
        int y = __shfl_up(x, off);
        if (lane >= off) x += y;
    }
    __shared__ int wsum[16];
    __shared__ int woff[17];
    if (lane == 63) wsum[wid] = x;
    __syncthreads();
    if (tid == 0) {
        int acc = 0;
        #pragma unroll
        for (int i = 0; i < 16; ++i) { woff[i] = acc; acc += wsum[i]; }
        woff[16] = acc;
    }
    __syncthreads();
    int threadExcl = woff[wid] + x - local;
    #pragma unroll
    for (int i = 0; i < CHUNK; ++i) {
        int idx = base + i;
        if (idx < NNODES) {
            int p = threadExcl + vals[i];
            rowptr[idx] = p;
            cursor[idx] = p;
        }
    }
    if (tid == SCAN_T - 1) rowptr[NNODES] = woff[16];
}

// ---------------- CSR build: scatter edge records (src, w) sorted by dst ----------------
__global__ __launch_bounds__(256) void k_scatter(const int* __restrict__ ei,
                                                 const float* __restrict__ pos,
                                                 const float* __restrict__ shift,
                                                 int* __restrict__ cursor,
                                                 float2* __restrict__ rec)
{
    int e = blockIdx.x * 256 + threadIdx.x;
    if (e >= NEDGES) return;
    int s = ei[e], d = ei[NEDGES + e];
    float rx = pos[3*s+0] - (pos[3*d+0] + shift[3*e+0]);
    float ry = pos[3*s+1] - (pos[3*d+1] + shift[3*e+1]);
    float rz = pos[3*s+2] - (pos[3*d+2] + shift[3*e+2]);
    float w = sqrtf(rx*rx + ry*ry + rz*rz);
    int slot = atomicAdd(&cursor[d], 1);
    rec[slot] = make_float2(__int_as_float(s), w);
}

// ---------------- gather-aggregate: one wave per dst node ----------------
__global__ __launch_bounds__(256) void k_gather(const float2* __restrict__ rec,
                                                const int* __restrict__ rowptr,
                                                const float* __restrict__ hf,
                                                const float* __restrict__ tableI,
                                                float* __restrict__ agg)
{
    int node = blockIdx.x * 4 + (threadIdx.x >> 6);
    int lane = threadIdx.x & 63;
    int beg = rowptr[node], end = rowptr[node + 1];
    const float SCALE = (float)(TPTS - 1) / WMAX;
    float2 acc = make_float2(0.f, 0.f);
    int k = beg;
    for (; k + 2 <= end; k += 2) {
        float2 r0 = rec[k];
        float2 r1 = rec[k + 1];
        int   s0 = __float_as_int(r0.x);
        int   s1 = __float_as_int(r1.x);
        float w0 = r0.y, w1 = r1.y;
        float t0 = fminf(w0 * SCALE, (float)(TPTS - 1));
        float t1 = fminf(w1 * SCALE, (float)(TPTS - 1));
        int i0 = (int)t0; if (i0 > TPTS - 2) i0 = TPTS - 2;
        int i1 = (int)t1; if (i1 > TPTS - 2) i1 = TPTS - 2;
        float fr0 = t0 - (float)i0;
        float fr1 = t1 - (float)i1;
        float4 ta = *((const float4*)(tableI + (size_t)i0 * 256) + lane);
        float4 tb = *((const float4*)(tableI + (size_t)i1 * 256) + lane);
        float2 h0 = *(const float2*)(hf + (size_t)s0 * HID + lane * 2);
        float2 h1 = *(const float2*)(hf + (size_t)s1 * HID + lane * 2);
        float C0 = 0.5f * (__cosf(w0 * (PI_F / 8.0f)) + 1.0f);
        float C1 = 0.5f * (__cosf(w1 * (PI_F / 8.0f)) + 1.0f);
        float f0a = fmaf(fr0, ta.y, ta.x) * C0;
        float f0b = fmaf(fr0, ta.w, ta.z) * C0;
        float f1a = fmaf(fr1, tb.y, tb.x) * C1;
        float f1b = fmaf(fr1, tb.w, tb.z) * C1;
        acc.x = fmaf(f0a, h0.x, acc.x);
        acc.y = fmaf(f0b, h0.y, acc.y);
        acc.x = fmaf(f1a, h1.x, acc.x);
        acc.y = fmaf(f1b, h1.y, acc.y);
    }
    if (k < end) {
        float2 r0 = rec[k];
        int   s0 = __float_as_int(r0.x);
        float w0 = r0.y;
        float t0 = fminf(w0 * SCALE, (float)(TPTS - 1));
        int i0 = (int)t0; if (i0 > TPTS - 2) i0 = TPTS - 2;
        float fr0 = t0 - (float)i0;
        float4 ta = *((const float4*)(tableI + (size_t)i0 * 256) + lane);
        float2 h0 = *(const float2*)(hf + (size_t)s0 * HID + lane * 2);
        float C0 = 0.5f * (__cosf(w0 * (PI_F / 8.0f)) + 1.0f);
        float f0a = fmaf(fr0, ta.y, ta.x) * C0;
        float f0b = fmaf(fr0, ta.w, ta.z) * C0;
        acc.x = fmaf(f0a, h0.x, acc.x);
        acc.y = fmaf(f0b, h0.y, acc.y);
    }
    *(float2*)(agg + (size_t)node * HID + lane * 2) = acc;
}

// ---------------- node GEMM: out[r] = A[r] @ W (+bias) ----------------
__global__ __launch_bounds__(256) void k_node_gemm(const float* __restrict__ A,
                                                   const float* __restrict__ W,
                                                   const float* __restrict__ bias,
                                                   float* __restrict__ out)
{
    __shared__ float sA[64 * 132];
    int r0 = blockIdx.x * 64;
    int tid = threadIdx.x;
    for (int idx = tid; idx < 64 * 32; idx += 256) {
        int r = idx >> 5, c4 = idx & 31;
        int row = r0 + r;
        float4 v = make_float4(0.f, 0.f, 0.f, 0.f);
        if (row < NNODES) v = *(const float4*)(A + (size_t)row * HID + c4 * 4);
        *(float4*)(&sA[r * 132 + c4 * 4]) = v;
    }
    __syncthreads();
    int tx = tid & 15, ty = tid >> 4;
    int cc = tx * 8, ee = ty * 4;
    float acc[4][8];
    if (bias) {
        float4 b0 = *(const float4*)(bias + cc);
        float4 b1 = *(const float4*)(bias + cc + 4);
        #pragma unroll
        for (int e = 0; e < 4; ++e) {
            acc[e][0]=b0.x; acc[e][1]=b0.y; acc[e][2]=b0.z; acc[e][3]=b0.w;
            acc[e][4]=b1.x; acc[e][5]=b1.y; acc[e][6]=b1.z; acc[e][7]=b1.w;
        }
    } else {
        #pragma unroll
        for (int e = 0; e < 4; ++e)
            #pragma unroll
            for (int c = 0; c < 8; ++c) acc[e][c] = 0.f;
    }
    for (int j = 0; j < HID; ++j) {
        float a[4];
        #pragma unroll
        for (int e = 0; e < 4; ++e) a[e] = sA[(ee + e) * 132 + j];
        float4 w0 = *(const float4*)(W + (size_t)j * HID + cc);
        float4 w1 = *(const float4*)(W + (size_t)j * HID + cc + 4);
        float wv[8] = {w0.x,w0.y,w0.z,w0.w,w1.x,w1.y,w1.z,w1.w};
        #pragma unroll
        for (int e = 0; e < 4; ++e)
            #pragma unroll
            for (int c = 0; c < 8; ++c)
                acc[e][c] = fmaf(a[e], wv[c], acc[e][c]);
    }
    #pragma unroll
    for (int e = 0; e < 4; ++e) {
        int row = r0 + ee + e;
        if (row < NNODES) {
            *(float4*)(out + (size_t)row * HID + cc)     = make_float4(acc[e][0], acc[e][1], acc[e][2], acc[e][3]);
            *(float4*)(out + (size_t)row * HID + cc + 4) = make_float4(acc[e][4], acc[e][5], acc[e][6], acc[e][7]);
        }
    }
}

// ---------------- node update: h += ssp(agg@W2+b2)@L+lb ----------------
__global__ __launch_bounds__(256) void k_node_update(const float* __restrict__ agg,
                                                     const float* __restrict__ W,
                                                     const float* __restrict__ B,
                                                     const float* __restrict__ L,
                                                     const float* __restrict__ LB,
                                                     float* __restrict__ h)
{
    __shared__ float sA[64 * 132];
    __shared__ float sT[64 * 132];
    int r0 = blockIdx.x * 64;
    int tid = threadIdx.x;
    for (int idx = tid; idx < 64 * 32; idx += 256) {
        int r = idx >> 5, c4 = idx & 31;
        int row = r0 + r;
        float4 v = make_float4(0.f, 0.f, 0.f, 0.f);
        if (row < NNODES) v = *(const float4*)(agg + (size_t)row * HID + c4 * 4);
        *(float4*)(&sA[r * 132 + c4 * 4]) = v;
    }
    __syncthreads();
    int tx = tid & 15, ty = tid >> 4;
    int cc = tx * 8, ee = ty * 4;
    float acc[4][8];
    {
        float4 b0 = *(const float4*)(B + cc);
        float4 b1 = *(const float4*)(B + cc + 4);
        #pragma unroll
        for (int e = 0; e < 4; ++e) {
            acc[e][0]=b0.x; acc[e][1]=b0.y; acc[e][2]=b0.z; acc[e][3]=b0.w;
            acc[e][4]=b1.x; acc[e][5]=b1.y; acc[e][6]=b1.z; acc[e][7]=b1.w;
        }
    }
    for (int j = 0; j < HID; ++j) {
        float a[4];
        #pragma unroll
        for (int e = 0; e < 4; ++e) a[e] = sA[(ee + e) * 132 + j];
        float4 w0 = *(const float4*)(W + (size_t)j * HID + cc);
        float4 w1 = *(const float4*)(W + (size_t)j * HID + cc + 4);
        float wv[8] = {w0.x,w0.y,w0.z,w0.w,w1.x,w1.y,w1.z,w1.w};
        #pragma unroll
        for (int e = 0; e < 4; ++e)
            #pragma unroll
            for (int c = 0; c < 8; ++c)
                acc[e][c] = fmaf(a[e], wv[c], acc[e][c]);
    }
    #pragma unroll
    for (int e = 0; e < 4; ++e)
        #pragma unroll
        for (int c = 0; c < 8; ++c)
            sT[(ee + e) * 132 + cc + c] = ssp(acc[e][c]);
    __syncthreads();
    float acc2[4][8];
    {
        float4 b0 = *(const float4*)(LB + cc);
        float4 b1 = *(const float4*)(LB + cc + 4);
        #pragma unroll
        for (int e = 0; e < 4; ++e) {
            acc2[e][0]=b0.x; acc2[e][1]=b0.y; acc2[e][2]=b0.z; acc2[e][3]=b0.w;
            acc2[e][4]=b1.x; acc2[e][5]=b1.y; acc2[e][6]=b1.z; acc2[e][7]=b1.w;
        }
    }
    for (int j = 0; j < HID; ++j) {
        float a[4];
        #pragma unroll
        for (int e = 0; e < 4; ++e) a[e] = sT[(ee + e) * 132 + j];
        float4 w0 = *(const float4*)(L + (size_t)j * HID + cc);
        float4 w1 = *(const float4*)(L + (size_t)j * HID + cc + 4);
        float wv[8] = {w0.x,w0.y,w0.z,w0.w,w1.x,w1.y,w1.z,w1.w};
        #pragma unroll
        for (int e = 0; e < 4; ++e)
            #pragma unroll
            for (int c = 0; c < 8; ++c)
                acc2[e][c] = fmaf(a[e], wv[c], acc2[e][c]);
    }
    #pragma unroll
    for (int e = 0; e < 4; ++e) {
        int row = r0 + ee + e;
        if (row < NNODES) {
            float4* hp0 = (float4*)(h + (size_t)row * HID + cc);
            float4* hp1 = (float4*)(h + (size_t)row * HID + cc + 4);
            float4 h0 = *hp0, h1 = *hp1;
            h0.x += acc2[e][0]; h0.y += acc2[e][1]; h0.z += acc2[e][2]; h0.w += acc2[e][3];
            h1.x += acc2[e][4]; h1.y += acc2[e][5]; h1.z += acc2[e][6]; h1.w += acc2[e][7];
            *hp0 = h0; *hp1 = h1;
        }
    }
}

// ---------------- head: GEMM-tiled, fused ssp+dot+atomic ----------------
__global__ __launch_bounds__(256) void k_head(const float* __restrict__ h,
                                              const float* __restrict__ w1,
                                              const float* __restrict__ b1,
                                              const float* __restrict__ w2,
                                              const float* __restrict__ b2,
                                              const int* __restrict__ batch,
                                              float* __restrict__ sums_pad)
{
    __shared__ float sA[64 * 132];
    int r0 = blockIdx.x * 64;
    int tid = threadIdx.x;
    for (int idx = tid; idx < 64 * 32; idx += 256) {
        int r = idx >> 5, c4 = idx & 31;
        int row = r0 + r;
        float4 v = make_float4(0.f, 0.f, 0.f, 0.f);
        if (row < NNODES) v = *(const float4*)(h + (size_t)row * HID + c4 * 4);
        *(float4*)(&sA[r * 132 + c4 * 4]) = v;
    }
    __syncthreads();
    int tx = tid & 7, ty = tid >> 3;     // 8 col-groups x 32 row-groups
    int cc = tx * 8, ee = ty * 2;
    float acc[2][8];
    {
        float4 b0 = *(const float4*)(b1 + cc);
        float4 bb = *(const float4*)(b1 + cc + 4);
        #pragma unroll
        for (int e = 0; e < 2; ++e) {
            acc[e][0]=b0.x; acc[e][1]=b0.y; acc[e][2]=b0.z; acc[e][3]=b0.w;
            acc[e][4]=bb.x; acc[e][5]=bb.y; acc[e][6]=bb.z; acc[e][7]=bb.w;
        }
    }
    #pragma unroll 4
    for (int j = 0; j < HID; ++j) {
        float a0 = sA[(ee + 0) * 132 + j];
        float a1 = sA[(ee + 1) * 132 + j];
        float4 w0 = *(const float4*)(w1 + (size_t)j * 64 + cc);
        float4 wv1 = *(const float4*)(w1 + (size_t)j * 64 + cc + 4);
        float wv[8] = {w0.x,w0.y,w0.z,w0.w,wv1.x,wv1.y,wv1.z,wv1.w};
        #pragma unroll
        for (int c = 0; c < 8; ++c) {
            acc[0][c] = fmaf(a0, wv[c], acc[0][c]);
            acc[1][c] = fmaf(a1, wv[c], acc[1][c]);
        }
    }
    float4 w2a = *(const float4*)(w2 + cc);
    float4 w2b = *(const float4*)(w2 + cc + 4);
    float w2v[8] = {w2a.x,w2a.y,w2a.z,w2a.w,w2b.x,w2b.y,w2b.z,w2b.w};
    float bias2 = b2[0];
    #pragma unroll
    for (int e = 0; e < 2; ++e) {
        float part = 0.f;
        #pragma unroll
        for (int c = 0; c < 8; ++c) part = fmaf(ssp(acc[e][c]), w2v[c], part);
        part += __shfl_down(part, 4, 8);
        part += __shfl_down(part, 2, 8);
        part += __shfl_down(part, 1, 8);
        if (tx == 0) {
            int row = r0 + ee + e;
            if (row < NNODES) {
                int b = batch[row];
                atomicAdd(&sums_pad[b * 16], part + bias2);
            }
        }
    }
}

// ---------------- final: counts via binary search on sorted batch ----------------
__global__ void k_final(const float* __restrict__ sums_pad,
                        const int* __restrict__ batch,
                        float* __restrict__ out)
{
    int g = threadIdx.x;
    if (g >= NGRAPHS) return;
    int lo = 0, hi = NNODES;
    while (lo < hi) { int mid = (lo + hi) >> 1; if (batch[mid] < g) lo = mid + 1; else hi = mid; }
    int a = lo;
    lo = 0; hi = NNODES;
    while (lo < hi) { int mid = (lo + hi) >> 1; if (batch[mid] < g + 1) lo = mid + 1; else hi = mid; }
    float cnt = (float)(lo - a);
    out[g] = sums_pad[g * 16] / fmaxf(cnt, 1.0f);
}

extern "C" void kernel_launch(void* const* d_in, const int* in_sizes, int n_in,
                              void* d_out, int out_size, void* d_ws, size_t ws_size,
                              hipStream_t stream)
{
    const float* pos     = (const float*)d_in[0];
    const float* shift   = (const float*)d_in[1];
    const float* emb     = (const float*)d_in[2];
    const float* mlp_w1  = (const float*)d_in[3];
    const float* mlp_b1  = (const float*)d_in[4];
    const float* mlp_w2  = (const float*)d_in[5];
    const float* mlp_b2  = (const float*)d_in[6];
    const float* cf_w1   = (const float*)d_in[7];
    const float* cf_w2   = (const float*)d_in[8];
    const float* cf_b2   = (const float*)d_in[9];
    const float* lin_w   = (const float*)d_in[10];
    const float* lin_b   = (const float*)d_in[11];
    const float* head_w1 = (const float*)d_in[12];
    const float* head_b1 = (const float*)d_in[13];
    const float* head_w2 = (const float*)d_in[14];
    const float* head_b2 = (const float*)d_in[15];
    const int*   z       = (const int*)d_in[16];
    const int*   ei      = (const int*)d_in[17];
    const int*   batch   = (const int*)d_in[18];
    float* out = (float*)d_out;

    float* ws = (float*)d_ws;
    size_t off = 0;
    float*  h       = ws + off; off += (size_t)NNODES * HID;
    float*  hf      = ws + off; off += (size_t)NNODES * HID;
    float*  agg     = ws + off; off += (size_t)NNODES * HID;
    float*  rawT    = ws + off; off += (size_t)3 * TPTS * HID;
    float*  tableI  = ws + off; off += (size_t)3 * TPTS * HID * 2;
    float2* rec     = (float2*)(ws + off); off += (size_t)2 * NEDGES;
    int*    rowptr  = (int*)(ws + off); off += NNODES + 1;
    int*    deg     = (int*)(ws + off); off += NNODES;
    int*    cursor  = (int*)(ws + off); off += NNODES;
    float*  sums_pad= ws + off; off += NGRAPHS * 16;

    hipMemsetAsync(deg, 0, NNODES * sizeof(int), stream);
    hipMemsetAsync(sums_pad, 0, NGRAPHS * 16 * sizeof(float), stream);

    k_hist<<<(NEDGES + 255) / 256, 256, 0, stream>>>(ei, deg);
    k_scan<<<1, SCAN_T, 0, stream>>>(deg, rowptr, cursor);
    k_scatter<<<(NEDGES + 255) / 256, 256, 0, stream>>>(ei, pos, shift, cursor, rec);

    k_init_h<<<NNODES * HID / 256, 256, 0, stream>>>(emb, z, h);
    k_table<<<3 * TPTS, 128, 0, stream>>>(mlp_w1, mlp_b1, mlp_w2, mlp_b2, rawT);
    k_tdelta<<<(3 * TPTS * HID) / 256, 256, 0, stream>>>(rawT, tableI);

    for (int i = 0; i < NITER; ++i) {
        k_node_gemm<<<(NNODES + 63) / 64, 256, 0, stream>>>(h, cf_w1 + (size_t)i * HID * HID, nullptr, hf);
        k_gather<<<NNODES / 4, 256, 0, stream>>>(rec, rowptr, hf, tableI + (size_t)i * TPTS * HID * 2, agg);
        k_node_update<<<(NNODES + 63) / 64, 256, 0, stream>>>(agg, cf_w2 + (size_t)i * HID * HID,
                                                              cf_b2 + (size_t)i * HID,
                                                              lin_w + (size_t)i * HID * HID,
                                                              lin_b + (size_t)i * HID, h);
    }
    k_head<<<(NNODES + 63) / 64, 256, 0, stream>>>(h, head_w1, head_b1, head_w2, head_b2, batch, sums_pad);
    k_final<<<1, 128, 0, stream>>>(sums_pad, batch, out);
}

// Round 5
// 1077.060 us; speedup vs baseline: 8.3675x; 1.1389x over previous
//
#include <hip/hip_runtime.h>
#include <hip/hip_fp16.h>
#include <math.h>

#define NNODES  50000
#define NEDGES  1600000
#define NGRAPHS 128
#define HID     128
#define NG      50
#define NITER   3
#define TPTS    2048
#define WMAX    12.0f
#define PI_F    3.14159265358979323846f

__device__ __forceinline__ float ssp(float x) {
    float sp = fmaxf(x, 0.0f) + log1pf(expf(-fabsf(x)));
    return sp - 0.69314718055994530942f;
}

// ---------------- h = emb[z] ----------------
__global__ __launch_bounds__(256) void k_init_h(const float* __restrict__ emb,
                                                const int* __restrict__ z,
                                                float* __restrict__ h)
{
    int idx = blockIdx.x * 256 + threadIdx.x;
    int n = idx >> 7, c = idx & 127;
    h[idx] = emb[(z[n] << 7) + c];
}

// ---------------- LUT build (fp32 raw) ----------------
__global__ __launch_bounds__(128) void k_table(const float* __restrict__ W1,
                                               const float* __restrict__ B1,
                                               const float* __restrict__ W2,
                                               const float* __restrict__ B2,
                                               float* __restrict__ table)
{
    int it = blockIdx.x / TPTS;
    int pt = blockIdx.x - it * TPTS;
    const float* W1i = W1 + (size_t)it * NG * HID;
    const float* B1i = B1 + (size_t)it * HID;
    const float* W2i = W2 + (size_t)it * HID * HID;
    const float* B2i = B2 + (size_t)it * HID;

    float w = pt * (WMAX / (float)(TPTS - 1));
    __shared__ float sEA[NG];
    __shared__ float sT1[HID];
    int k = threadIdx.x;
    if (k < NG) {
        float dx = 8.0f / 49.0f;
        float coeff = -0.5f / (dx * dx);
        float diff = w - (float)k * dx;
        sEA[k] = expf(coeff * diff * diff);
    }
    __syncthreads();
    float acc = B1i[k];
    for (int g = 0; g < NG; ++g) acc = fmaf(sEA[g], W1i[g * HID + k], acc);
    sT1[k] = ssp(acc);
    __syncthreads();
    float acc2 = B2i[k];
    for (int j = 0; j < HID; ++j) acc2 = fmaf(sT1[j], W2i[j * HID + k], acc2);
    table[(size_t)blockIdx.x * HID + k] = acc2;
}

// ---------------- interleave (val, delta) as fp16 ----------------
__global__ __launch_bounds__(256) void k_tdelta(const float* __restrict__ raw,
                                                __half* __restrict__ ti)
{
    int idx = blockIdx.x * 256 + threadIdx.x;   // 3*TPTS*128
    int c = idx & 127;
    int pt_it = idx >> 7;
    int pt = pt_it & (TPTS - 1);
    float v = raw[idx];
    float nv = (pt == TPTS - 1) ? v : raw[idx + HID];
    ti[(size_t)pt_it * 256 + c * 2]     = __float2half(v);
    ti[(size_t)pt_it * 256 + c * 2 + 1] = __float2half(nv - v);
}

// ---------------- CSR build: histogram of dst ----------------
__global__ __launch_bounds__(256) void k_hist(const int* __restrict__ ei,
                                              int* __restrict__ deg)
{
    int e = blockIdx.x * 256 + threadIdx.x;
    if (e >= NEDGES) return;
    atomicAdd(&deg[ei[NEDGES + e]], 1);
}

// ---------------- CSR build: exclusive scan, chunk-per-thread ----------------
#define SCAN_T 1024
#define CHUNK  49
__global__ __launch_bounds__(SCAN_T) void k_scan(const int* __restrict__ deg,
                                                 int* __restrict__ rowptr,
                                                 int* __restrict__ cursor)
{
    int tid = threadIdx.x;
    int base = tid * CHUNK;
    int vals[CHUNK];
    int local = 0;
    #pragma unroll
    for (int i = 0; i < CHUNK; ++i) {
        int idx = base + i;
        int v = (idx < NNODES) ? deg[idx] : 0;
        vals[i] = local;
        local += v;
    }
    int lane = tid & 63, wid = tid >> 6;
    int x = local;
    #pragma unroll
    for (int off = 1; off < 64; off <<= 1) {
        int y = __shfl_up(x, off);
        if (lane >= off) x += y;
    }
    __shared__ int wsum[16];
    __shared__ int woff[17];
    if (lane == 63) wsum[wid] = x;
    __syncthreads();
    if (tid == 0) {
        int acc = 0;
        #pragma unroll
        for (int i = 0; i < 16; ++i) { woff[i] = acc; acc += wsum[i]; }
        woff[16] = acc;
    }
    __syncthreads();
    int threadExcl = woff[wid] + x - local;
    #pragma unroll
    for (int i = 0; i < CHUNK; ++i) {
        int idx = base + i;
        if (idx < NNODES) {
            int p = threadExcl + vals[i];
            rowptr[idx] = p;
            cursor[idx] = p;
        }
    }
    if (tid == SCAN_T - 1) rowptr[NNODES] = woff[16];
}

// ---------------- CSR build: scatter edge records (src, w) sorted by dst ----------------
__global__ __launch_bounds__(256) void k_scatter(const int* __restrict__ ei,
                                                 const float* __restrict__ pos,
                                                 const float* __restrict__ shift,
                                                 int* __restrict__ cursor,
                                                 float2* __restrict__ rec)
{
    int e = blockIdx.x * 256 + threadIdx.x;
    if (e >= NEDGES) return;
    int s = ei[e], d = ei[NEDGES + e];
    float rx = pos[3*s+0] - (pos[3*d+0] + shift[3*e+0]);
    float ry = pos[3*s+1] - (pos[3*d+1] + shift[3*e+1]);
    float rz = pos[3*s+2] - (pos[3*d+2] + shift[3*e+2]);
    float w = sqrtf(rx*rx + ry*ry + rz*rz);
    int slot = atomicAdd(&cursor[d], 1);
    rec[slot] = make_float2(__int_as_float(s), w);
}

// ---------------- gather helper: one edge's contribution ----------------
__device__ __forceinline__ void edge_contrib(float2 r, int lane,
                                             const __half2* __restrict__ hfH,
                                             const __half* __restrict__ tableH,
                                             float& ax, float& ay)
{
    int   s = __float_as_int(r.x);
    float w = r.y;
    const float SCALE = (float)(TPTS - 1) / WMAX;
    float t = fminf(w * SCALE, (float)(TPTS - 1));
    int i0 = (int)t; if (i0 > TPTS - 2) i0 = TPTS - 2;
    float fr = t - (float)i0;
    float C = 0.5f * (__cosf(w * (PI_F / 8.0f)) + 1.0f);
    uint2 tv = *((const uint2*)(tableH + (size_t)i0 * 256) + lane);
    __half2 hv = hfH[(size_t)s * 64 + lane];
    float2 p0 = __half22float2(*(__half2*)&tv.x);   // val0, d0
    float2 p1 = __half22float2(*(__half2*)&tv.y);   // val1, d1
    float2 hf2 = __half22float2(hv);
    ax = fmaf(fmaf(fr, p0.y, p0.x) * C, hf2.x, ax);
    ay = fmaf(fmaf(fr, p1.y, p1.x) * C, hf2.y, ay);
}

// ---------------- gather-aggregate: one wave per dst node, 4-edge unroll ----------------
__global__ __launch_bounds__(256) void k_gather(const float2* __restrict__ rec,
                                                const int* __restrict__ rowptr,
                                                const __half2* __restrict__ hfH,
                                                const __half* __restrict__ tableH,
                                                float* __restrict__ agg)
{
    int node = blockIdx.x * 4 + (threadIdx.x >> 6);
    int lane = threadIdx.x & 63;
    int beg = rowptr[node], end = rowptr[node + 1];
    float ax0 = 0.f, ay0 = 0.f, ax1 = 0.f, ay1 = 0.f;
    int k = beg;
    for (; k + 4 <= end; k += 4) {
        float2 r0 = rec[k];
        float2 r1 = rec[k + 1];
        float2 r2 = rec[k + 2];
        float2 r3 = rec[k + 3];
        edge_contrib(r0, lane, hfH, tableH, ax0, ay0);
        edge_contrib(r1, lane, hfH, tableH, ax1, ay1);
        edge_contrib(r2, lane, hfH, tableH, ax0, ay0);
        edge_contrib(r3, lane, hfH, tableH, ax1, ay1);
    }
    for (; k < end; ++k) {
        float2 r0 = rec[k];
        edge_contrib(r0, lane, hfH, tableH, ax0, ay0);
    }
    *(float2*)(agg + (size_t)node * HID + lane * 2) = make_float2(ax0 + ax1, ay0 + ay1);
}

// ---------------- node GEMM (fp16 out, no bias): hf = h @ W ----------------
__global__ __launch_bounds__(512) void k_node_gemm(const float* __restrict__ A,
                                                   const float* __restrict__ W,
                                                   __half* __restrict__ outH)
{
    __shared__ float sA[128 * 132];
    int r0 = blockIdx.x * 128;
    int tid = threadIdx.x;
    for (int idx = tid; idx < 128 * 32; idx += 512) {
        int r = idx >> 5, c4 = idx & 31;
        int row = r0 + r;
        float4 v = make_float4(0.f, 0.f, 0.f, 0.f);
        if (row < NNODES) v = *(const float4*)(A + (size_t)row * HID + c4 * 4);
        *(float4*)(&sA[r * 132 + c4 * 4]) = v;
    }
    __syncthreads();
    int tx = tid & 15, ty = tid >> 4;      // 16 col-groups x 32 row-groups
    int cc = tx * 8, ee = ty * 4;
    float acc[4][8];
    #pragma unroll
    for (int e = 0; e < 4; ++e)
        #pragma unroll
        for (int c = 0; c < 8; ++c) acc[e][c] = 0.f;
    for (int j = 0; j < HID; ++j) {
        float a[4];
        #pragma unroll
        for (int e = 0; e < 4; ++e) a[e] = sA[(ee + e) * 132 + j];
        float4 w0 = *(const float4*)(W + (size_t)j * HID + cc);
        float4 w1 = *(const float4*)(W + (size_t)j * HID + cc + 4);
        float wv[8] = {w0.x,w0.y,w0.z,w0.w,w1.x,w1.y,w1.z,w1.w};
        #pragma unroll
        for (int e = 0; e < 4; ++e)
            #pragma unroll
            for (int c = 0; c < 8; ++c)
                acc[e][c] = fmaf(a[e], wv[c], acc[e][c]);
    }
    #pragma unroll
    for (int e = 0; e < 4; ++e) {
        int row = r0 + ee + e;
        if (row < NNODES) {
            __half2 p0 = __floats2half2_rn(acc[e][0], acc[e][1]);
            __half2 p1 = __floats2half2_rn(acc[e][2], acc[e][3]);
            __half2 p2 = __floats2half2_rn(acc[e][4], acc[e][5]);
            __half2 p3 = __floats2half2_rn(acc[e][6], acc[e][7]);
            uint4 pk;
            pk.x = *(unsigned*)&p0; pk.y = *(unsigned*)&p1;
            pk.z = *(unsigned*)&p2; pk.w = *(unsigned*)&p3;
            *(uint4*)(outH + (size_t)row * HID + cc) = pk;
        }
    }
}

// ---------------- node update: h += ssp(agg@W2+b2)@L+lb (in-place LDS reuse) ----------------
__global__ __launch_bounds__(512) void k_node_update(const float* __restrict__ agg,
                                                     const float* __restrict__ W,
                                                     const float* __restrict__ B,
                                                     const float* __restrict__ L,
                                                     const float* __restrict__ LB,
                                                     float* __restrict__ h)
{
    __shared__ float sA[128 * 132];
    int r0 = blockIdx.x * 128;
    int tid = threadIdx.x;
    for (int idx = tid; idx < 128 * 32; idx += 512) {
        int r = idx >> 5, c4 = idx & 31;
        int row = r0 + r;
        float4 v = make_float4(0.f, 0.f, 0.f, 0.f);
        if (row < NNODES) v = *(const float4*)(agg + (size_t)row * HID + c4 * 4);
        *(float4*)(&sA[r * 132 + c4 * 4]) = v;
    }
    __syncthreads();
    int tx = tid & 15, ty = tid >> 4;
    int cc = tx * 8, ee = ty * 4;
    float acc[4][8];
    {
        float4 b0 = *(const float4*)(B + cc);
        float4 b1 = *(const float4*)(B + cc + 4);
        #pragma unroll
        for (int e = 0; e < 4; ++e) {
            acc[e][0]=b0.x; acc[e][1]=b0.y; acc[e][2]=b0.z; acc[e][3]=b0.w;
            acc[e][4]=b1.x; acc[e][5]=b1.y; acc[e][6]=b1.z; acc[e][7]=b1.w;
        }
    }
    for (int j = 0; j < HID; ++j) {
        float a[4];
        #pragma unroll
        for (int e = 0; e < 4; ++e) a[e] = sA[(ee + e) * 132 + j];
        float4 w0 = *(const float4*)(W + (size_t)j * HID + cc);
        float4 w1 = *(const float4*)(W + (size_t)j * HID + cc + 4);
        float wv[8] = {w0.x,w0.y,w0.z,w0.w,w1.x,w1.y,w1.z,w1.w};
        #pragma unroll
        for (int e = 0; e < 4; ++e)
            #pragma unroll
            for (int c = 0; c < 8; ++c)
                acc[e][c] = fmaf(a[e], wv[c], acc[e][c]);
    }
    __syncthreads();   // all reads of sA done -> reuse in place for ssp intermediate
    #pragma unroll
    for (int e = 0; e < 4; ++e)
        #pragma unroll
        for (int c = 0; c < 8; ++c)
            sA[(ee + e) * 132 + cc + c] = ssp(acc[e][c]);
    __syncthreads();
    float acc2[4][8];
    {
        float4 b0 = *(const float4*)(LB + cc);
        float4 b1 = *(const float4*)(LB + cc + 4);
        #pragma unroll
        for (int e = 0; e < 4; ++e) {
            acc2[e][0]=b0.x; acc2[e][1]=b0.y; acc2[e][2]=b0.z; acc2[e][3]=b0.w;
            acc2[e][4]=b1.x; acc2[e][5]=b1.y; acc2[e][6]=b1.z; acc2[e][7]=b1.w;
        }
    }
    for (int j = 0; j < HID; ++j) {
        float a[4];
        #pragma unroll
        for (int e = 0; e < 4; ++e) a[e] = sA[(ee + e) * 132 + j];
        float4 w0 = *(const float4*)(L + (size_t)j * HID + cc);
        float4 w1 = *(const float4*)(L + (size_t)j * HID + cc + 4);
        float wv[8] = {w0.x,w0.y,w0.z,w0.w,w1.x,w1.y,w1.z,w1.w};
        #pragma unroll
        for (int e = 0; e < 4; ++e)
            #pragma unroll
            for (int c = 0; c < 8; ++c)
                acc2[e][c] = fmaf(a[e], wv[c], acc2[e][c]);
    }
    #pragma unroll
    for (int e = 0; e < 4; ++e) {
        int row = r0 + ee + e;
        if (row < NNODES) {
            float4* hp0 = (float4*)(h + (size_t)row * HID + cc);
            float4* hp1 = (float4*)(h + (size_t)row * HID + cc + 4);
            float4 h0 = *hp0, h1 = *hp1;
            h0.x += acc2[e][0]; h0.y += acc2[e][1]; h0.z += acc2[e][2]; h0.w += acc2[e][3];
            h1.x += acc2[e][4]; h1.y += acc2[e][5]; h1.z += acc2[e][6]; h1.w += acc2[e][7];
            *hp0 = h0; *hp1 = h1;
        }
    }
}

// ---------------- head: 128-row tile, fused ssp+dot+atomic ----------------
__global__ __launch_bounds__(512) void k_head(const float* __restrict__ h,
                                              const float* __restrict__ w1,
                                              const float* __restrict__ b1,
                                              const float* __restrict__ w2,
                                              const float* __restrict__ b2,
                                              const int* __restrict__ batch,
                                              float* __restrict__ sums_pad)
{
    __shared__ float sA[128 * 132];
    int r0 = blockIdx.x * 128;
    int tid = threadIdx.x;
    for (int idx = tid; idx < 128 * 32; idx += 512) {
        int r = idx >> 5, c4 = idx & 31;
        int row = r0 + r;
        float4 v = make_float4(0.f, 0.f, 0.f, 0.f);
        if (row < NNODES) v = *(const float4*)(h + (size_t)row * HID + c4 * 4);
        *(float4*)(&sA[r * 132 + c4 * 4]) = v;
    }
    __syncthreads();
    int tx = tid & 7, ty = tid >> 3;    // 8 col-groups x 64 row-groups
    int cc = tx * 8, ee = ty * 2;
    float acc[2][8];
    {
        float4 b0 = *(const float4*)(b1 + cc);
        float4 bb = *(const float4*)(b1 + cc + 4);
        #pragma unroll
        for (int e = 0; e < 2; ++e) {
            acc[e][0]=b0.x; acc[e][1]=b0.y; acc[e][2]=b0.z; acc[e][3]=b0.w;
            acc[e][4]=bb.x; acc[e][5]=bb.y; acc[e][6]=bb.z; acc[e][7]=bb.w;
        }
    }
    #pragma unroll 4
    for (int j = 0; j < HID; ++j) {
        float a0 = sA[(ee + 0) * 132 + j];
        float a1 = sA[(ee + 1) * 132 + j];
        float4 w0 = *(const float4*)(w1 + (size_t)j * 64 + cc);
        float4 wv1 = *(const float4*)(w1 + (size_t)j * 64 + cc + 4);
        float wv[8] = {w0.x,w0.y,w0.z,w0.w,wv1.x,wv1.y,wv1.z,wv1.w};
        #pragma unroll
        for (int c = 0; c < 8; ++c) {
            acc[0][c] = fmaf(a0, wv[c], acc[0][c]);
            acc[1][c] = fmaf(a1, wv[c], acc[1][c]);
        }
    }
    float4 w2a = *(const float4*)(w2 + cc);
    float4 w2b = *(const float4*)(w2 + cc + 4);
    float w2v[8] = {w2a.x,w2a.y,w2a.z,w2a.w,w2b.x,w2b.y,w2b.z,w2b.w};
    float bias2 = b2[0];
    #pragma unroll
    for (int e = 0; e < 2; ++e) {
        float part = 0.f;
        #pragma unroll
        for (int c = 0; c < 8; ++c) part = fmaf(ssp(acc[e][c]), w2v[c], part);
        part += __shfl_down(part, 4, 8);
        part += __shfl_down(part, 2, 8);
        part += __shfl_down(part, 1, 8);
        if (tx == 0) {
            int row = r0 + ee + e;
            if (row < NNODES) {
                int b = batch[row];
                atomicAdd(&sums_pad[b * 16], part + bias2);
            }
        }
    }
}

// ---------------- final: counts via binary search on sorted batch ----------------
__global__ void k_final(const float* __restrict__ sums_pad,
                        const int* __restrict__ batch,
                        float* __restrict__ out)
{
    int g = threadIdx.x;
    if (g >= NGRAPHS) return;
    int lo = 0, hi = NNODES;
    while (lo < hi) { int mid = (lo + hi) >> 1; if (batch[mid] < g) lo = mid + 1; else hi = mid; }
    int a = lo;
    lo = 0; hi = NNODES;
    while (lo < hi) { int mid = (lo + hi) >> 1; if (batch[mid] < g + 1) lo = mid + 1; else hi = mid; }
    float cnt = (float)(lo - a);
    out[g] = sums_pad[g * 16] / fmaxf(cnt, 1.0f);
}

extern "C" void kernel_launch(void* const* d_in, const int* in_sizes, int n_in,
                              void* d_out, int out_size, void* d_ws, size_t ws_size,
                              hipStream_t stream)
{
    const float* pos     = (const float*)d_in[0];
    const float* shift   = (const float*)d_in[1];
    const float* emb     = (const float*)d_in[2];
    const float* mlp_w1  = (const float*)d_in[3];
    const float* mlp_b1  = (const float*)d_in[4];
    const float* mlp_w2  = (const float*)d_in[5];
    const float* mlp_b2  = (const float*)d_in[6];
    const float* cf_w1   = (const float*)d_in[7];
    const float* cf_w2   = (const float*)d_in[8];
    const float* cf_b2   = (const float*)d_in[9];
    const float* lin_w   = (const float*)d_in[10];
    const float* lin_b   = (const float*)d_in[11];
    const float* head_w1 = (const float*)d_in[12];
    const float* head_b1 = (const float*)d_in[13];
    const float* head_w2 = (const float*)d_in[14];
    const float* head_b2 = (const float*)d_in[15];
    const int*   z       = (const int*)d_in[16];
    const int*   ei      = (const int*)d_in[17];
    const int*   batch   = (const int*)d_in[18];
    float* out = (float*)d_out;

    float* ws = (float*)d_ws;
    size_t off = 0;
    float*  h       = ws + off; off += (size_t)NNODES * HID;
    __half* hfH     = (__half*)(ws + off); off += (size_t)(NNODES + 48) * HID / 2;
    float*  agg     = ws + off; off += (size_t)NNODES * HID;
    float*  rawT    = ws + off; off += (size_t)3 * TPTS * HID;
    __half* tableH  = (__half*)(ws + off); off += (size_t)3 * TPTS * HID;  // (val,delta) pairs: 3*TPTS*128*2 halves
    float2* rec     = (float2*)(ws + off); off += (size_t)2 * NEDGES;
    int*    rowptr  = (int*)(ws + off); off += NNODES + 1;
    int*    deg     = (int*)(ws + off); off += NNODES;
    int*    cursor  = (int*)(ws + off); off += NNODES;
    float*  sums_pad= ws + off; off += NGRAPHS * 16;

    hipMemsetAsync(deg, 0, NNODES * sizeof(int), stream);
    hipMemsetAsync(sums_pad, 0, NGRAPHS * 16 * sizeof(float), stream);

    k_hist<<<(NEDGES + 255) / 256, 256, 0, stream>>>(ei, deg);
    k_scan<<<1, SCAN_T, 0, stream>>>(deg, rowptr, cursor);
    k_scatter<<<(NEDGES + 255) / 256, 256, 0, stream>>>(ei, pos, shift, cursor, rec);

    k_init_h<<<NNODES * HID / 256, 256, 0, stream>>>(emb, z, h);
    k_table<<<3 * TPTS, 128, 0, stream>>>(mlp_w1, mlp_b1, mlp_w2, mlp_b2, rawT);
    k_tdelta<<<(3 * TPTS * HID) / 256, 256, 0, stream>>>(rawT, tableH);

    int gblk = (NNODES + 127) / 128;
    for (int i = 0; i < NITER; ++i) {
        k_node_gemm<<<gblk, 512, 0, stream>>>(h, cf_w1 + (size_t)i * HID * HID, hfH);
        k_gather<<<NNODES / 4, 256, 0, stream>>>(rec, rowptr, (const __half2*)hfH,
                                                 tableH + (size_t)i * TPTS * HID * 2, agg);
        k_node_update<<<gblk, 512, 0, stream>>>(agg, cf_w2 + (size_t)i * HID * HID,
                                                cf_b2 + (size_t)i * HID,
                                                lin_w + (size_t)i * HID * HID,
                                                lin_b + (size_t)i * HID, h);
    }
    k_head<<<gblk, 512, 0, stream>>>(h, head_w1, head_b1, head_w2, head_b2, batch, sums_pad);
    k_final<<<1, 128, 0, stream>>>(sums_pad, batch, out);
}

// Round 6
// 1050.768 us; speedup vs baseline: 8.5769x; 1.0250x over previous
//
#include <hip/hip_runtime.h>
#include <hip/hip_fp16.h>
#include <math.h>

#define NNODES  50000
#define NEDGES  1600000
#define NGRAPHS 128
#define HID     128
#define NG      50
#define NITER   3
#define TPTS    2048
#define WMAX    12.0f
#define PI_F    3.14159265358979323846f

typedef __attribute__((ext_vector_type(4))) _Float16 half4;
typedef __attribute__((ext_vector_type(4))) float   f32x4;

__device__ __forceinline__ float ssp(float x) {
    float sp = fmaxf(x, 0.0f) + log1pf(expf(-fabsf(x)));
    return sp - 0.69314718055994530942f;
}

// ---------------- h = emb[z] (fp32 master + fp16 shadow) ----------------
__global__ __launch_bounds__(256) void k_init_h(const float* __restrict__ emb,
                                                const int* __restrict__ z,
                                                float* __restrict__ h,
                                                _Float16* __restrict__ hH)
{
    int idx = blockIdx.x * 256 + threadIdx.x;
    int n = idx >> 7, c = idx & 127;
    float v = emb[(z[n] << 7) + c];
    h[idx] = v;
    hH[idx] = (_Float16)v;
}

// ---------------- weight transpose+cast: out[it][c][j] = in[it][j][c] fp16 ----------------
__global__ __launch_bounds__(128) void k_wt(const float* __restrict__ in,
                                            _Float16* __restrict__ out)
{
    int it = blockIdx.x >> 7, c = blockIdx.x & 127, j = threadIdx.x;
    out[(size_t)it * 16384 + c * 128 + j] = (_Float16)in[(size_t)it * 16384 + j * 128 + c];
}

// ---------------- LUT build (fp32 raw) ----------------
__global__ __launch_bounds__(128) void k_table(const float* __restrict__ W1,
                                               const float* __restrict__ B1,
                                               const float* __restrict__ W2,
                                               const float* __restrict__ B2,
                                               float* __restrict__ table)
{
    int it = blockIdx.x / TPTS;
    int pt = blockIdx.x - it * TPTS;
    const float* W1i = W1 + (size_t)it * NG * HID;
    const float* B1i = B1 + (size_t)it * HID;
    const float* W2i = W2 + (size_t)it * HID * HID;
    const float* B2i = B2 + (size_t)it * HID;

    float w = pt * (WMAX / (float)(TPTS - 1));
    __shared__ float sEA[NG];
    __shared__ float sT1[HID];
    int k = threadIdx.x;
    if (k < NG) {
        float dx = 8.0f / 49.0f;
        float coeff = -0.5f / (dx * dx);
        float diff = w - (float)k * dx;
        sEA[k] = expf(coeff * diff * diff);
    }
    __syncthreads();
    float acc = B1i[k];
    for (int g = 0; g < NG; ++g) acc = fmaf(sEA[g], W1i[g * HID + k], acc);
    sT1[k] = ssp(acc);
    __syncthreads();
    float acc2 = B2i[k];
    for (int j = 0; j < HID; ++j) acc2 = fmaf(sT1[j], W2i[j * HID + k], acc2);
    table[(size_t)blockIdx.x * HID + k] = acc2;
}

// ---------------- interleave (val, delta) as fp16 ----------------
__global__ __launch_bounds__(256) void k_tdelta(const float* __restrict__ raw,
                                                __half* __restrict__ ti)
{
    int idx = blockIdx.x * 256 + threadIdx.x;   // 3*TPTS*128
    int c = idx & 127;
    int pt_it = idx >> 7;
    int pt = pt_it & (TPTS - 1);
    float v = raw[idx];
    float nv = (pt == TPTS - 1) ? v : raw[idx + HID];
    ti[(size_t)pt_it * 256 + c * 2]     = __float2half(v);
    ti[(size_t)pt_it * 256 + c * 2 + 1] = __float2half(nv - v);
}

// ---------------- CSR build: histogram of dst ----------------
__global__ __launch_bounds__(256) void k_hist(const int* __restrict__ ei,
                                              int* __restrict__ deg)
{
    int e = blockIdx.x * 256 + threadIdx.x;
    if (e >= NEDGES) return;
    atomicAdd(&deg[ei[NEDGES + e]], 1);
}

// ---------------- CSR build: exclusive scan, chunk-per-thread ----------------
#define SCAN_T 1024
#define CHUNK  49
__global__ __launch_bounds__(SCAN_T) void k_scan(const int* __restrict__ deg,
                                                 int* __restrict__ rowptr,
                                                 int* __restrict__ cursor)
{
    int tid = threadIdx.x;
    int base = tid * CHUNK;
    int vals[CHUNK];
    int local = 0;
    #pragma unroll
    for (int i = 0; i < CHUNK; ++i) {
        int idx = base + i;
        int v = (idx < NNODES) ? deg[idx] : 0;
        vals[i] = local;
        local += v;
    }
    int lane = tid & 63, wid = tid >> 6;
    int x = local;
    #pragma unroll
    for (int off = 1; off < 64; off <<= 1) {
        int y = __shfl_up(x, off);
        if (lane >= off) x += y;
    }
    __shared__ int wsum[16];
    __shared__ int woff[17];
    if (lane == 63) wsum[wid] = x;
    __syncthreads();
    if (tid == 0) {
        int acc = 0;
        #pragma unroll
        for (int i = 0; i < 16; ++i) { woff[i] = acc; acc += wsum[i]; }
        woff[16] = acc;
    }
    __syncthreads();
    int threadExcl = woff[wid] + x - local;
    #pragma unroll
    for (int i = 0; i < CHUNK; ++i) {
        int idx = base + i;
        if (idx < NNODES) {
            int p = threadExcl + vals[i];
            rowptr[idx] = p;
            cursor[idx] = p;
        }
    }
    if (tid == SCAN_T - 1) rowptr[NNODES] = woff[16];
}

// ---------------- CSR build: scatter edge records (src, w) sorted by dst ----------------
__global__ __launch_bounds__(256) void k_scatter(const int* __restrict__ ei,
                                                 const float* __restrict__ pos,
                                                 const float* __restrict__ shift,
                                                 int* __restrict__ cursor,
                                                 float2* __restrict__ rec)
{
    int e = blockIdx.x * 256 + threadIdx.x;
    if (e >= NEDGES) return;
    int s = ei[e], d = ei[NEDGES + e];
    float rx = pos[3*s+0] - (pos[3*d+0] + shift[3*e+0]);
    float ry = pos[3*s+1] - (pos[3*d+1] + shift[3*e+1]);
    float rz = pos[3*s+2] - (pos[3*d+2] + shift[3*e+2]);
    float w = sqrtf(rx*rx + ry*ry + rz*rz);
    int slot = atomicAdd(&cursor[d], 1);
    rec[slot] = make_float2(__int_as_float(s), w);
}

// ---------------- gather helper: one edge's contribution ----------------
__device__ __forceinline__ void edge_contrib(float2 r, int lane,
                                             const __half2* __restrict__ hfH,
                                             const __half* __restrict__ tableH,
                                             float& ax, float& ay)
{
    int   s = __float_as_int(r.x);
    float w = r.y;
    const float SCALE = (float)(TPTS - 1) / WMAX;
    float t = fminf(w * SCALE, (float)(TPTS - 1));
    int i0 = (int)t; if (i0 > TPTS - 2) i0 = TPTS - 2;
    float fr = t - (float)i0;
    float C = 0.5f * (__cosf(w * (PI_F / 8.0f)) + 1.0f);
    uint2 tv = *((const uint2*)(tableH + (size_t)i0 * 256) + lane);
    __half2 hv = hfH[(size_t)s * 64 + lane];
    float2 p0 = __half22float2(*(__half2*)&tv.x);   // val0, d0
    float2 p1 = __half22float2(*(__half2*)&tv.y);   // val1, d1
    float2 hf2 = __half22float2(hv);
    ax = fmaf(fmaf(fr, p0.y, p0.x) * C, hf2.x, ax);
    ay = fmaf(fmaf(fr, p1.y, p1.x) * C, hf2.y, ay);
}

// ---------------- gather-aggregate: one wave per dst node, fp16 agg out ----------------
__global__ __launch_bounds__(256) void k_gather(const float2* __restrict__ rec,
                                                const int* __restrict__ rowptr,
                                                const __half2* __restrict__ hfH,
                                                const __half* __restrict__ tableH,
                                                __half2* __restrict__ aggH)
{
    int node = blockIdx.x * 4 + (threadIdx.x >> 6);
    int lane = threadIdx.x & 63;
    int beg = rowptr[node], end = rowptr[node + 1];
    float ax0 = 0.f, ay0 = 0.f, ax1 = 0.f, ay1 = 0.f;
    int k = beg;
    for (; k + 4 <= end; k += 4) {
        float2 r0 = rec[k];
        float2 r1 = rec[k + 1];
        float2 r2 = rec[k + 2];
        float2 r3 = rec[k + 3];
        edge_contrib(r0, lane, hfH, tableH, ax0, ay0);
        edge_contrib(r1, lane, hfH, tableH, ax1, ay1);
        edge_contrib(r2, lane, hfH, tableH, ax0, ay0);
        edge_contrib(r3, lane, hfH, tableH, ax1, ay1);
    }
    for (; k < end; ++k) {
        float2 r0 = rec[k];
        edge_contrib(r0, lane, hfH, tableH, ax0, ay0);
    }
    aggH[(size_t)node * 64 + lane] = __floats2half2_rn(ax0 + ax1, ay0 + ay1);
}

// ---------------- MFMA GEMM: outH = hH @ Wt^T (Wt is [col][k] fp16) ----------------
// block: 256 thr = 4 waves; wave owns 16 rows x 128 cols (8 col-tiles)
__global__ __launch_bounds__(256) void k_ngemm_mfma(const _Float16* __restrict__ hH,
                                                    const _Float16* __restrict__ Wt,
                                                    _Float16* __restrict__ outH)
{
    int tid = threadIdx.x;
    int wave = tid >> 6, l = tid & 63;
    int lr = l & 15, lg = l >> 4;
    int r0 = blockIdx.x * 64 + wave * 16;
    f32x4 acc[8];
    #pragma unroll
    for (int ct = 0; ct < 8; ++ct) acc[ct] = (f32x4){0.f, 0.f, 0.f, 0.f};
    const _Float16* aRow = hH + (size_t)(r0 + lr) * HID;
    #pragma unroll
    for (int kk = 0; kk < 8; ++kk) {
        half4 a = *(const half4*)(aRow + kk * 16 + lg * 4);
        #pragma unroll
        for (int ct = 0; ct < 8; ++ct) {
            half4 b = *(const half4*)(Wt + (size_t)(ct * 16 + lr) * HID + kk * 16 + lg * 4);
            acc[ct] = __builtin_amdgcn_mfma_f32_16x16x16f16(a, b, acc[ct], 0, 0, 0);
        }
    }
    #pragma unroll
    for (int ct = 0; ct < 8; ++ct) {
        #pragma unroll
        for (int r = 0; r < 4; ++r) {
            int row = r0 + lg * 4 + r;
            if (row < NNODES) outH[(size_t)row * HID + ct * 16 + lr] = (_Float16)acc[ct][r];
        }
    }
}

// ---------------- MFMA fused update: h += ssp(aggH@W2t + b2) @ Lt + lb ----------------
__global__ __launch_bounds__(256) void k_update_mfma(const _Float16* __restrict__ aggH,
                                                     const _Float16* __restrict__ W2t,
                                                     const float* __restrict__ B2,
                                                     const _Float16* __restrict__ Lt,
                                                     const float* __restrict__ LB,
                                                     float* __restrict__ h,
                                                     _Float16* __restrict__ hH)
{
    __shared__ _Float16 sT[64 * 128];     // 16 KB, XOR-swizzled
    int tid = threadIdx.x;
    int wave = tid >> 6, l = tid & 63;
    int lr = l & 15, lg = l >> 4;
    int r0 = blockIdx.x * 64 + wave * 16;

    f32x4 acc[8];
    #pragma unroll
    for (int ct = 0; ct < 8; ++ct) acc[ct] = (f32x4){0.f, 0.f, 0.f, 0.f};
    const _Float16* aRow = aggH + (size_t)(r0 + lr) * HID;
    #pragma unroll
    for (int kk = 0; kk < 8; ++kk) {
        half4 a = *(const half4*)(aRow + kk * 16 + lg * 4);
        #pragma unroll
        for (int ct = 0; ct < 8; ++ct) {
            half4 b = *(const half4*)(W2t + (size_t)(ct * 16 + lr) * HID + kk * 16 + lg * 4);
            acc[ct] = __builtin_amdgcn_mfma_f32_16x16x16f16(a, b, acc[ct], 0, 0, 0);
        }
    }
    // ssp + bias -> swizzled LDS fp16
    #pragma unroll
    for (int ct = 0; ct < 8; ++ct) {
        #pragma unroll
        for (int r = 0; r < 4; ++r) {
            int rl = wave * 16 + lg * 4 + r;
            int col = ct * 16 + lr;
            float v = ssp(acc[ct][r] + B2[col]);
            int byte = rl * 256 + col * 2;
            byte ^= (rl & 7) << 4;
            *(_Float16*)((char*)sT + byte) = (_Float16)v;
        }
    }
    __syncthreads();
    f32x4 acc2[8];
    #pragma unroll
    for (int ct = 0; ct < 8; ++ct) acc2[ct] = (f32x4){0.f, 0.f, 0.f, 0.f};
    int rl2 = wave * 16 + lr;
    #pragma unroll
    for (int kk = 0; kk < 8; ++kk) {
        int byte = rl2 * 256 + (kk * 16 + lg * 4) * 2;
        byte ^= (rl2 & 7) << 4;
        half4 a = *(const half4*)((char*)sT + byte);
        #pragma unroll
        for (int ct = 0; ct < 8; ++ct) {
            half4 b = *(const half4*)(Lt + (size_t)(ct * 16 + lr) * HID + kk * 16 + lg * 4);
            acc2[ct] = __builtin_amdgcn_mfma_f32_16x16x16f16(a, b, acc2[ct], 0, 0, 0);
        }
    }
    #pragma unroll
    for (int ct = 0; ct < 8; ++ct) {
        #pragma unroll
        for (int r = 0; r < 4; ++r) {
            int row = r0 + lg * 4 + r;
            int col = ct * 16 + lr;
            if (row < NNODES) {
                float hv = h[(size_t)row * HID + col] + acc2[ct][r] + LB[col];
                h[(size_t)row * HID + col] = hv;
                hH[(size_t)row * HID + col] = (_Float16)hv;
            }
        }
    }
}

// ---------------- head: 128-row tile, fused ssp+dot+atomic ----------------
__global__ __launch_bounds__(512) void k_head(const float* __restrict__ h,
                                              const float* __restrict__ w1,
                                              const float* __restrict__ b1,
                                              const float* __restrict__ w2,
                                              const float* __restrict__ b2,
                                              const int* __restrict__ batch,
                                              float* __restrict__ sums_pad)
{
    __shared__ float sA[128 * 132];
    int r0 = blockIdx.x * 128;
    int tid = threadIdx.x;
    for (int idx = tid; idx < 128 * 32; idx += 512) {
        int r = idx >> 5, c4 = idx & 31;
        int row = r0 + r;
        float4 v = make_float4(0.f, 0.f, 0.f, 0.f);
        if (row < NNODES) v = *(const float4*)(h + (size_t)row * HID + c4 * 4);
        *(float4*)(&sA[r * 132 + c4 * 4]) = v;
    }
    __syncthreads();
    int tx = tid & 7, ty = tid >> 3;
    int cc = tx * 8, ee = ty * 2;
    float acc[2][8];
    {
        float4 b0 = *(const float4*)(b1 + cc);
        float4 bb = *(const float4*)(b1 + cc + 4);
        #pragma unroll
        for (int e = 0; e < 2; ++e) {
            acc[e][0]=b0.x; acc[e][1]=b0.y; acc[e][2]=b0.z; acc[e][3]=b0.w;
            acc[e][4]=bb.x; acc[e][5]=bb.y; acc[e][6]=bb.z; acc[e][7]=bb.w;
        }
    }
    #pragma unroll 4
    for (int j = 0; j < HID; ++j) {
        float a0 = sA[(ee + 0) * 132 + j];
        float a1 = sA[(ee + 1) * 132 + j];
        float4 w0 = *(const float4*)(w1 + (size_t)j * 64 + cc);
        float4 wv1 = *(const float4*)(w1 + (size_t)j * 64 + cc + 4);
        float wv[8] = {w0.x,w0.y,w0.z,w0.w,wv1.x,wv1.y,wv1.z,wv1.w};
        #pragma unroll
        for (int c = 0; c < 8; ++c) {
            acc[0][c] = fmaf(a0, wv[c], acc[0][c]);
            acc[1][c] = fmaf(a1, wv[c], acc[1][c]);
        }
    }
    float4 w2a = *(const float4*)(w2 + cc);
    float4 w2b = *(const float4*)(w2 + cc + 4);
    float w2v[8] = {w2a.x,w2a.y,w2a.z,w2a.w,w2b.x,w2b.y,w2b.z,w2b.w};
    float bias2 = b2[0];
    #pragma unroll
    for (int e = 0; e < 2; ++e) {
        float part = 0.f;
        #pragma unroll
        for (int c = 0; c < 8; ++c) part = fmaf(ssp(acc[e][c]), w2v[c], part);
        part += __shfl_down(part, 4, 8);
        part += __shfl_down(part, 2, 8);
        part += __shfl_down(part, 1, 8);
        if (tx == 0) {
            int row = r0 + ee + e;
            if (row < NNODES) {
                int b = batch[row];
                atomicAdd(&sums_pad[b * 16], part + bias2);
            }
        }
    }
}

// ---------------- final: counts via binary search on sorted batch ----------------
__global__ void k_final(const float* __restrict__ sums_pad,
                        const int* __restrict__ batch,
                        float* __restrict__ out)
{
    int g = threadIdx.x;
    if (g >= NGRAPHS) return;
    int lo = 0, hi = NNODES;
    while (lo < hi) { int mid = (lo + hi) >> 1; if (batch[mid] < g) lo = mid + 1; else hi = mid; }
    int a = lo;
    lo = 0; hi = NNODES;
    while (lo < hi) { int mid = (lo + hi) >> 1; if (batch[mid] < g + 1) lo = mid + 1; else hi = mid; }
    float cnt = (float)(lo - a);
    out[g] = sums_pad[g * 16] / fmaxf(cnt, 1.0f);
}

extern "C" void kernel_launch(void* const* d_in, const int* in_sizes, int n_in,
                              void* d_out, int out_size, void* d_ws, size_t ws_size,
                              hipStream_t stream)
{
    const float* pos     = (const float*)d_in[0];
    const float* shift   = (const float*)d_in[1];
    const float* emb     = (const float*)d_in[2];
    const float* mlp_w1  = (const float*)d_in[3];
    const float* mlp_b1  = (const float*)d_in[4];
    const float* mlp_w2  = (const float*)d_in[5];
    const float* mlp_b2  = (const float*)d_in[6];
    const float* cf_w1   = (const float*)d_in[7];
    const float* cf_w2   = (const float*)d_in[8];
    const float* cf_b2   = (const float*)d_in[9];
    const float* lin_w   = (const float*)d_in[10];
    const float* lin_b   = (const float*)d_in[11];
    const float* head_w1 = (const float*)d_in[12];
    const float* head_b1 = (const float*)d_in[13];
    const float* head_w2 = (const float*)d_in[14];
    const float* head_b2 = (const float*)d_in[15];
    const int*   z       = (const int*)d_in[16];
    const int*   ei      = (const int*)d_in[17];
    const int*   batch   = (const int*)d_in[18];
    float* out = (float*)d_out;

    float* ws = (float*)d_ws;
    size_t off = 0;
    float*    h       = ws + off; off += (size_t)NNODES * HID;
    _Float16* hH      = (_Float16*)(ws + off); off += (size_t)(NNODES + 64) * HID / 2;
    _Float16* hfH     = (_Float16*)(ws + off); off += (size_t)(NNODES + 64) * HID / 2;
    _Float16* aggH    = (_Float16*)(ws + off); off += (size_t)(NNODES + 64) * HID / 2;
    float*    rawT    = ws + off; off += (size_t)3 * TPTS * HID;
    __half*   tableH  = (__half*)(ws + off); off += (size_t)3 * TPTS * HID;
    _Float16* w1t     = (_Float16*)(ws + off); off += (size_t)3 * HID * HID / 2;
    _Float16* w2t     = (_Float16*)(ws + off); off += (size_t)3 * HID * HID / 2;
    _Float16* lwt     = (_Float16*)(ws + off); off += (size_t)3 * HID * HID / 2;
    float2*   rec     = (float2*)(ws + off); off += (size_t)2 * NEDGES;
    int*      rowptr  = (int*)(ws + off); off += NNODES + 1;
    int*      deg     = (int*)(ws + off); off += NNODES;
    int*      cursor  = (int*)(ws + off); off += NNODES;
    float*    sums_pad= ws + off; off += NGRAPHS * 16;

    hipMemsetAsync(deg, 0, NNODES * sizeof(int), stream);
    hipMemsetAsync(sums_pad, 0, NGRAPHS * 16 * sizeof(float), stream);

    k_hist<<<(NEDGES + 255) / 256, 256, 0, stream>>>(ei, deg);
    k_scan<<<1, SCAN_T, 0, stream>>>(deg, rowptr, cursor);
    k_scatter<<<(NEDGES + 255) / 256, 256, 0, stream>>>(ei, pos, shift, cursor, rec);

    k_init_h<<<NNODES * HID / 256, 256, 0, stream>>>(emb, z, h, hH);
    k_table<<<3 * TPTS, 128, 0, stream>>>(mlp_w1, mlp_b1, mlp_w2, mlp_b2, rawT);
    k_tdelta<<<(3 * TPTS * HID) / 256, 256, 0, stream>>>(rawT, tableH);
    k_wt<<<3 * 128, 128, 0, stream>>>(cf_w1, w1t);
    k_wt<<<3 * 128, 128, 0, stream>>>(cf_w2, w2t);
    k_wt<<<3 * 128, 128, 0, stream>>>(lin_w, lwt);

    int gblk = (NNODES + 63) / 64;
    for (int i = 0; i < NITER; ++i) {
        k_ngemm_mfma<<<gblk, 256, 0, stream>>>(hH, w1t + (size_t)i * HID * HID, hfH);
        k_gather<<<NNODES / 4, 256, 0, stream>>>(rec, rowptr, (const __half2*)hfH,
                                                 tableH + (size_t)i * TPTS * HID * 2,
                                                 (__half2*)aggH);
        k_update_mfma<<<gblk, 256, 0, stream>>>(aggH, w2t + (size_t)i * HID * HID,
                                                cf_b2 + (size_t)i * HID,
                                                lwt + (size_t)i * HID * HID,
                                                lin_b + (size_t)i * HID, h, hH);
    }
    k_head<<<(NNODES + 127) / 128, 512, 0, stream>>>(h, head_w1, head_b1, head_w2, head_b2, batch, sums_pad);
    k_final<<<1, 128, 0, stream>>>(sums_pad, batch, out);
}